// Round 4
// baseline (2040.132 us; speedup 1.0000x reference)
//
#include <hip/hip_runtime.h>
#include <hip/hip_bf16.h>

#define NNODES 200000
#define NEDGES 3200000
#define NBUCK 782            // ceil(NNODES/256)
#define EPS 1e-5f

typedef __bf16 bf16x8 __attribute__((ext_vector_type(8)));
typedef float  f32x4  __attribute__((ext_vector_type(4)));

__device__ __forceinline__ float bflo(unsigned u) { return __uint_as_float(u << 16); }
__device__ __forceinline__ float bfhi(unsigned u) { return __uint_as_float(u & 0xffff0000u); }
__device__ __forceinline__ unsigned short f2b(float f) {
    return __builtin_bit_cast(unsigned short, __float2bfloat16(f));
}
__device__ __forceinline__ unsigned pk2(float a, float b) {
    return (unsigned)f2b(a) | ((unsigned)f2b(b) << 16);
}

// ---------------- CSR build ----------------
__global__ __launch_bounds__(256) void k_hist(const int* __restrict__ row, int* __restrict__ deg) {
    int e = blockIdx.x * 256 + threadIdx.x;
    if (e < NEDGES) atomicAdd(&deg[row[e]], 1);
}

__global__ __launch_bounds__(256) void k_scan1(const int* __restrict__ deg, int* __restrict__ offs,
                                               int* __restrict__ bsum, float* __restrict__ dinv) {
    __shared__ int s[256];
    int i = blockIdx.x * 256 + threadIdx.x;
    int d = 0;
    if (i < NNODES) {
        d = deg[i];                          // real edges only; self loop analytic
        dinv[i] = rsqrtf((float)(d + 1));
    }
    s[threadIdx.x] = d;
    __syncthreads();
    for (int off = 1; off < 256; off <<= 1) {
        int v = (threadIdx.x >= off) ? s[threadIdx.x - off] : 0;
        __syncthreads();
        s[threadIdx.x] += v;
        __syncthreads();
    }
    if (i < NNODES) offs[i + 1] = s[threadIdx.x];
    if (threadIdx.x == 255) bsum[blockIdx.x] = s[255];
    if (i == 0) offs[0] = 0;
}

__global__ __launch_bounds__(1024) void k_scan2(int* __restrict__ bsum, int nb) {
    __shared__ int s[1024];
    int t = threadIdx.x;
    int v = (t < nb) ? bsum[t] : 0;
    s[t] = v;
    __syncthreads();
    for (int off = 1; off < 1024; off <<= 1) {
        int u = (t >= off) ? s[t - off] : 0;
        __syncthreads();
        s[t] += u;
        __syncthreads();
    }
    if (t < nb) bsum[t] = s[t] - v;         // exclusive base
}

__global__ __launch_bounds__(256) void k_scan3(int* __restrict__ offs, const int* __restrict__ bsum) {
    int i = blockIdx.x * 256 + threadIdx.x;
    if (i < NNODES) offs[i + 1] += bsum[blockIdx.x];
}

// seed per-bucket cursors with the bucket's base CSR offset
__global__ __launch_bounds__(256) void k_binit(const int* __restrict__ offs, int* __restrict__ bcur) {
    int b = blockIdx.x * 256 + threadIdx.x;
    if (b < NBUCK) bcur[b] = offs[b * 256];
}

// pass 1: scatter edges into bucket-contiguous regions (write-combining friendly)
__global__ __launch_bounds__(256) void k_bin(const int* __restrict__ row, const int* __restrict__ col,
                                             int* __restrict__ bcur, unsigned* __restrict__ ebuf) {
    int i = blockIdx.x * 256 + threadIdx.x;
    if (i >= NEDGES) return;
    int r = row[i], c = col[i];
    int p = atomicAdd(&bcur[r >> 8], 1);
    ebuf[p] = ((unsigned)(r & 255) << 18) | (unsigned)c;   // col < 2^18
}

// pass 2: rank within bucket via LDS histogram, emit final CSR (bucket-local writes)
__global__ __launch_bounds__(256) void k_sort(const unsigned* __restrict__ ebuf,
                                              const int* __restrict__ offs,
                                              int* __restrict__ csr) {
    __shared__ int cnt[256];
    __shared__ int sofs[257];
    const int b = blockIdx.x;
    const int n0 = b * 256;
    const int t = threadIdx.x;
    const int nloc = min(256, NNODES - n0);
    cnt[t] = 0;
    sofs[t] = offs[min(n0 + t, NNODES)];
    if (t == 0) sofs[256] = offs[min(n0 + 256, NNODES)];
    __syncthreads();
    const int s = sofs[0], e = sofs[nloc];
    for (int i = s + t; i < e; i += 256) {
        unsigned v = ebuf[i];
        int nl = v >> 18;
        int rank = atomicAdd(&cnt[nl], 1);
        csr[sofs[nl] + rank] = (int)(v & 0x3FFFFu);
    }
}

// ---------------- cast x to bf16, prescaled by dinv ----------------
__global__ __launch_bounds__(256) void k_cast(const float* __restrict__ x,
                                              const float* __restrict__ dinv,
                                              uint4* __restrict__ xb) {
    size_t t = (size_t)blockIdx.x * 256 + threadIdx.x;   // one uint4 (8 bf16) per thread
    int n = (int)(t >> 4);                                // 16 threads per 128-feat row
    float d = dinv[n];
    const float4* xp = (const float4*)(x + t * 8);
    float4 a = xp[0], b = xp[1];
    uint4 o;
    o.x = pk2(a.x * d, a.y * d); o.y = pk2(a.z * d, a.w * d);
    o.z = pk2(b.x * d, b.y * d); o.w = pk2(b.z * d, b.w * d);
    xb[t] = o;
}

// ---------------- aggregation: bf16 prescaled, F=128 (layer 1) ----------------
__global__ __launch_bounds__(256) void k_aggf(const unsigned* __restrict__ xb,
                                              const int* __restrict__ offs,
                                              const int* __restrict__ csr,
                                              const float* __restrict__ dinv,
                                              unsigned* __restrict__ out) {
    const int lane = threadIdx.x & 63;
    const int node = blockIdx.x * 4 + (threadIdx.x >> 6);
    const unsigned* base = xb + lane;                     // row stride 64 uints
    unsigned us = base[(size_t)node * 64];
    float a0 = bflo(us), a1 = bfhi(us);                   // self term (prescaled)
    int p = offs[node];
    const int p1 = offs[node + 1];
    for (; p + 4 <= p1; p += 4) {
        int i0 = csr[p], i1 = csr[p + 1], i2 = csr[p + 2], i3 = csr[p + 3];
        unsigned u0 = base[(size_t)i0 * 64];
        unsigned u1 = base[(size_t)i1 * 64];
        unsigned u2 = base[(size_t)i2 * 64];
        unsigned u3 = base[(size_t)i3 * 64];
        a0 += bflo(u0) + bflo(u1) + bflo(u2) + bflo(u3);
        a1 += bfhi(u0) + bfhi(u1) + bfhi(u2) + bfhi(u3);
    }
    for (; p < p1; ++p) {
        unsigned u0 = base[(size_t)csr[p] * 64];
        a0 += bflo(u0); a1 += bfhi(u0);
    }
    const float d = dinv[node];
    out[(size_t)node * 64 + lane] = pk2(a0 * d, a1 * d);
}

// ---------------- aggregation: bf16 prescaled, F=256 (layer 2) ----------------
__global__ __launch_bounds__(256) void k_aggb(const uint2* __restrict__ in,
                                              const int* __restrict__ offs,
                                              const int* __restrict__ csr,
                                              const float* __restrict__ dinv,
                                              uint2* __restrict__ out) {
    const int lane = threadIdx.x & 63;
    const int node = blockIdx.x * 4 + (threadIdx.x >> 6);
    const uint2* base = in + lane;                        // row stride 64 uint2
    uint2 us = base[(size_t)node * 64];
    float a0 = bflo(us.x), a1 = bfhi(us.x), a2 = bflo(us.y), a3 = bfhi(us.y);
    int p = offs[node];
    const int p1 = offs[node + 1];
    for (; p + 4 <= p1; p += 4) {
        int i0 = csr[p], i1 = csr[p + 1], i2 = csr[p + 2], i3 = csr[p + 3];
        uint2 u0 = base[(size_t)i0 * 64];
        uint2 u1 = base[(size_t)i1 * 64];
        uint2 u2 = base[(size_t)i2 * 64];
        uint2 u3 = base[(size_t)i3 * 64];
        a0 += bflo(u0.x) + bflo(u1.x) + bflo(u2.x) + bflo(u3.x);
        a1 += bfhi(u0.x) + bfhi(u1.x) + bfhi(u2.x) + bfhi(u3.x);
        a2 += bflo(u0.y) + bflo(u1.y) + bflo(u2.y) + bflo(u3.y);
        a3 += bfhi(u0.y) + bfhi(u1.y) + bfhi(u2.y) + bfhi(u3.y);
    }
    for (; p < p1; ++p) {
        uint2 u0 = base[(size_t)csr[p] * 64];
        a0 += bflo(u0.x); a1 += bfhi(u0.x); a2 += bflo(u0.y); a3 += bfhi(u0.y);
    }
    const float d = dinv[node];
    uint2 o;
    o.x = pk2(a0 * d, a1 * d);
    o.y = pk2(a2 * d, a3 * d);
    out[(size_t)node * 64 + lane] = o;
}

// final layer: aggregate 40 bf16 prescaled feats, 3 edges/iter, + b3 + log_softmax
__global__ __launch_bounds__(256) void k_agg3(const unsigned* __restrict__ T3b,
                                              const int* __restrict__ offs,
                                              const int* __restrict__ csr,
                                              const float* __restrict__ dinv,
                                              const float* __restrict__ b3,
                                              float* __restrict__ out) {
    const int lane = threadIdx.x & 63;
    const int node = blockIdx.x * 4 + (threadIdx.x >> 6);
    const int grp = lane / 20;            // 0,1,2 (lanes 60-63 idle)
    const int f2 = lane - grp * 20;       // feat pair index
    const bool act = lane < 60;
    const unsigned* base = T3b + f2;      // row stride 20 uints
    float a0 = 0.f, a1 = 0.f;
    const int p1 = offs[node + 1];
    int q = offs[node] + grp;
    if (act) {
        if (grp == 0) {                   // self term
            unsigned u = base[(size_t)node * 20];
            a0 = bflo(u); a1 = bfhi(u);
        }
        while (q + 3 < p1) {
            int i0 = csr[q], i1 = csr[q + 3];
            unsigned u0 = base[(size_t)i0 * 20];
            unsigned u1 = base[(size_t)i1 * 20];
            a0 += bflo(u0) + bflo(u1);
            a1 += bfhi(u0) + bfhi(u1);
            q += 6;
        }
        if (q < p1) {
            unsigned u0 = base[(size_t)csr[q] * 20];
            a0 += bflo(u0); a1 += bfhi(u0);
        }
    }
    // reduce across the 3 lane groups (valid for lanes 0-19)
    float t0 = __shfl(a0, (lane + 20) & 63), t1 = __shfl(a0, (lane + 40) & 63);
    float s0 = __shfl(a1, (lane + 20) & 63), s1 = __shfl(a1, (lane + 40) & 63);
    a0 += t0 + t1;
    a1 += s0 + s1;
    const bool ok = lane < 20;
    const float d = dinv[node];
    float2 bb = ok ? *(const float2*)(b3 + 2 * f2) : make_float2(0.f, 0.f);
    float v0 = a0 * d + bb.x;
    float v1 = a1 * d + bb.y;
    float m = ok ? fmaxf(v0, v1) : -INFINITY;
#pragma unroll
    for (int o = 16; o >= 1; o >>= 1) m = fmaxf(m, __shfl_xor(m, o));
    float e = ok ? (__expf(v0 - m) + __expf(v1 - m)) : 0.f;
    float s = e;
#pragma unroll
    for (int o = 16; o >= 1; o >>= 1) s += __shfl_xor(s, o);
    float ls = __logf(s);
    if (ok) {
        float2 r = make_float2(v0 - m - ls, v1 - m - ls);
        *(float2*)(out + (size_t)node * 40 + 2 * f2) = r;
    }
}

// ---------------- W pre-swizzle (fp32 -> bf16 MFMA b-frag order) ----------------
__global__ __launch_bounds__(256) void k_prepw(const float* __restrict__ W,
                                               __hip_bfloat16* __restrict__ Wswz,
                                               int K, int NOUT, int NFRAG) {
    int t = blockIdx.x * 256 + threadIdx.x;
    int KSTEPS = K / 32;
    if (t >= NFRAG * KSTEPS * 64) return;
    int lane = t & 63;
    int ks = (t >> 6) % KSTEPS;
    int g  = (t >> 6) / KSTEPS;
    int c = lane & 15, q = lane >> 4;
    int col = g * 16 + c;
    int k0 = ks * 32 + q * 8;
    unsigned short vals[8];
#pragma unroll
    for (int j = 0; j < 8; ++j)
        vals[j] = (col < NOUT) ? f2b(W[(size_t)(k0 + j) * NOUT + col]) : (unsigned short)0;
    *(uint4*)((char*)Wswz + (size_t)t * 16) = __builtin_bit_cast(uint4, vals);
}

// ---------------- MFMA GEMM: C[M x NOUT] = A[M x K] @ W, optional dinv prescale ----------------
template <int K, int MW, int NW, int WNB, bool PRESCALE>
__global__ __launch_bounds__(MW * NW * 64) void k_gemm(const __hip_bfloat16* __restrict__ A,
                                                       const __hip_bfloat16* __restrict__ Wswz,
                                                       const float* __restrict__ dinvp,
                                                       unsigned short* __restrict__ Cout,
                                                       int M, int NOUT) {
    constexpr int KSTEPS = K / 32;
    const int lane = threadIdx.x & 63;
    const int wid  = threadIdx.x >> 6;
    const int wm = (wid % MW) * 64;
    const int wn = (wid / MW) * (WNB * 16);
    const long rowBase = (long)blockIdx.x * (MW * 64);
    const int cl = lane & 15, q = lane >> 4;

    const __hip_bfloat16* aptr[4];
#pragma unroll
    for (int mf = 0; mf < 4; ++mf) {
        long r = rowBase + wm + mf * 16 + cl;
        if (r > M - 1) r = M - 1;           // tail clamp (stores predicated)
        aptr[mf] = A + r * K + q * 8;
    }
    const __hip_bfloat16* bptr[WNB];
#pragma unroll
    for (int nf = 0; nf < WNB; ++nf) {
        int g = wn / 16 + nf;
        bptr[nf] = Wswz + (size_t)g * KSTEPS * 512 + (size_t)lane * 8;
    }

    f32x4 acc[4][WNB];
    const f32x4 z = {0.f, 0.f, 0.f, 0.f};
#pragma unroll
    for (int mf = 0; mf < 4; ++mf)
#pragma unroll
        for (int nf = 0; nf < WNB; ++nf) acc[mf][nf] = z;

#pragma unroll
    for (int ks = 0; ks < KSTEPS; ++ks) {
        bf16x8 a[4], b[WNB];
#pragma unroll
        for (int mf = 0; mf < 4; ++mf)
            a[mf] = __builtin_bit_cast(bf16x8, *(const uint4*)(aptr[mf] + ks * 32));
#pragma unroll
        for (int nf = 0; nf < WNB; ++nf)
            b[nf] = __builtin_bit_cast(bf16x8, *(const uint4*)(bptr[nf] + ks * 512));
#pragma unroll
        for (int mf = 0; mf < 4; ++mf)
#pragma unroll
            for (int nf = 0; nf < WNB; ++nf)
                acc[mf][nf] = __builtin_amdgcn_mfma_f32_16x16x32_bf16(a[mf], b[nf], acc[mf][nf], 0, 0, 0);
    }

#pragma unroll
    for (int mf = 0; mf < 4; ++mf)
#pragma unroll
        for (int i = 0; i < 4; ++i) {
            long row = rowBase + wm + mf * 16 + q * 4 + i;
            if (row >= M) continue;
            float dv = PRESCALE ? dinvp[row] : 1.0f;
#pragma unroll
            for (int nf = 0; nf < WNB; ++nf) {
                int col = wn + nf * 16 + cl;
                if (col < NOUT)
                    Cout[row * NOUT + col] = f2b(PRESCALE ? acc[mf][nf][i] * dv : acc[mf][nf][i]);
            }
        }
}

// ---------------- BN stats / params / apply ----------------
__global__ __launch_bounds__(256) void k_stats(const unsigned short* __restrict__ Zu,
                                               float* __restrict__ sums, float* __restrict__ sq) {
    const int t = threadIdx.x;
    const long r0 = (long)blockIdx.x * 256;
    float s = 0.f, s2 = 0.f;
    for (int i = 0; i < 256; ++i) {
        long r = r0 + i;
        if (r >= NNODES) break;
        float v = __uint_as_float((unsigned)Zu[r * 256 + t] << 16);
        s += v; s2 += v * v;
    }
    atomicAdd(&sums[t], s);
    atomicAdd(&sq[t], s2);
}

__global__ __launch_bounds__(256) void k_bnparams(const float* __restrict__ sums, const float* __restrict__ sq,
                                                  const float* __restrict__ gamma,
                                                  const float* __restrict__ beta,
                                                  float* __restrict__ scale, float* __restrict__ shift) {
    int t = threadIdx.x;
    float mu = sums[t] * (1.0f / NNODES);
    float var = sq[t] * (1.0f / NNODES) - mu * mu;
    if (var < 0.f) var = 0.f;
    float sc = gamma[t] * rsqrtf(var + EPS);
    scale[t] = sc;
    shift[t] = beta[t] - mu * sc;
}

__global__ __launch_bounds__(256) void k_bnrelu(const uint4* __restrict__ Z,
                                                const float* __restrict__ scale,
                                                const float* __restrict__ shift,
                                                uint4* __restrict__ H) {
    size_t t = (size_t)blockIdx.x * 256 + threadIdx.x;
    uint4 u = Z[t];
    int c0 = (int)((t * 8) & 255);
    float v[8] = {bflo(u.x), bfhi(u.x), bflo(u.y), bfhi(u.y),
                  bflo(u.z), bfhi(u.z), bflo(u.w), bfhi(u.w)};
    float r[8];
#pragma unroll
    for (int j = 0; j < 8; ++j) r[j] = fmaxf(0.f, v[j] * scale[c0 + j] + shift[c0 + j]);
    uint4 o;
    o.x = pk2(r[0], r[1]); o.y = pk2(r[2], r[3]); o.z = pk2(r[4], r[5]); o.w = pk2(r[6], r[7]);
    H[t] = o;
}

// ---------------- driver ----------------
extern "C" void kernel_launch(void* const* d_in, const int* in_sizes, int n_in,
                              void* d_out, int out_size, void* d_ws, size_t ws_size,
                              hipStream_t stream) {
    const float* x   = (const float*)d_in[0];
    const int*   ei  = (const int*)d_in[1];
    const float* W1  = (const float*)d_in[2];
    const float* g1  = (const float*)d_in[4];
    const float* be1 = (const float*)d_in[5];
    const float* W2  = (const float*)d_in[6];
    const float* g2  = (const float*)d_in[8];
    const float* be2 = (const float*)d_in[9];
    const float* W3  = (const float*)d_in[10];
    const float* b3  = (const float*)d_in[11];
    // b1 (d_in[3]) and b2 (d_in[7]) cancel exactly under BatchNorm — skipped.

    char* w = (char*)d_ws;
    size_t o = 0;
    auto alloc = [&](size_t b) { size_t r = o; o += (b + 255) & ~(size_t)255; return r; };
    int*   deg  = (int*)(w + alloc((size_t)NNODES * 4));
    int*   offs = (int*)(w + alloc((size_t)(NNODES + 1) * 4));
    float* dinv = (float*)(w + alloc((size_t)NNODES * 4));
    int*   bsum = (int*)(w + alloc(1024 * 4));
    int*   bcur = (int*)(w + alloc(NBUCK * 4));
    unsigned* ebuf = (unsigned*)(w + alloc((size_t)NEDGES * 4));
    int*   csr  = (int*)(w + alloc((size_t)NEDGES * 4));
    float* stats = (float*)(w + alloc(4 * 256 * 4));   // sums1,sq1,sums2,sq2
    float* bnp   = (float*)(w + alloc(4 * 256 * 4));   // scale1,shift1,scale2,shift2
    __hip_bfloat16* w1s  = (__hip_bfloat16*)(w + alloc(65536));
    __hip_bfloat16* w2s  = (__hip_bfloat16*)(w + alloc(131072));
    __hip_bfloat16* w3s  = (__hip_bfloat16*)(w + alloc(24576));
    __hip_bfloat16* xb   = (__hip_bfloat16*)(w + alloc((size_t)NNODES * 128 * 2)); // x bf16 prescaled
    __hip_bfloat16* buf0 = (__hip_bfloat16*)(w + alloc((size_t)NNODES * 128 * 2)); // y0, later T3' bf16
    __hip_bfloat16* buf1 = (__hip_bfloat16*)(w + alloc((size_t)NNODES * 256 * 2)); // Z1 -> Z2' -> h2
    __hip_bfloat16* buf2 = (__hip_bfloat16*)(w + alloc((size_t)NNODES * 256 * 2)); // h1 -> y2

    float* sums1 = stats;       float* sq1 = stats + 256;
    float* sums2 = stats + 512; float* sq2 = stats + 768;
    float* scale1 = bnp;        float* shift1 = bnp + 256;
    float* scale2 = bnp + 512;  float* shift2 = bnp + 768;

    hipMemsetAsync(deg, 0, (size_t)NNODES * 4, stream);
    hipMemsetAsync(stats, 0, 4 * 256 * 4, stream);

    const int SB = (NNODES + 255) / 256;  // 782
    k_hist<<<NEDGES / 256, 256, 0, stream>>>(ei, deg);
    k_scan1<<<SB, 256, 0, stream>>>(deg, offs, bsum, dinv);
    k_scan2<<<1, 1024, 0, stream>>>(bsum, SB);
    k_scan3<<<SB, 256, 0, stream>>>(offs, bsum);
    k_binit<<<(NBUCK + 255) / 256, 256, 0, stream>>>(offs, bcur);
    k_bin<<<NEDGES / 256, 256, 0, stream>>>(ei, ei + NEDGES, bcur, ebuf);
    k_sort<<<NBUCK, 256, 0, stream>>>(ebuf, offs, csr);
    k_cast<<<(NNODES * 128 / 8) / 256, 256, 0, stream>>>(x, dinv, (uint4*)xb);

    k_prepw<<<16, 256, 0, stream>>>(W1, w1s, 128, 256, 16);
    k_prepw<<<32, 256, 0, stream>>>(W2, w2s, 256, 256, 16);
    k_prepw<<<6, 256, 0, stream>>>(W3, w3s, 256, 40, 3);

    const dim3 g64((NNODES + 63) / 64, 1);   // 3125, 64-row blocks

    // layer 1 (aggregate-first on prescaled bf16 x)
    k_aggf<<<NNODES / 4, 256, 0, stream>>>((const unsigned*)xb, offs, csr, dinv, (unsigned*)buf0);
    k_gemm<128, 1, 4, 4, false><<<g64, 256, 0, stream>>>(buf0, w1s, nullptr, (unsigned short*)buf1, NNODES, 256);
    k_stats<<<SB, 256, 0, stream>>>((const unsigned short*)buf1, sums1, sq1);
    k_bnparams<<<1, 256, 0, stream>>>(sums1, sq1, g1, be1, scale1, shift1);
    k_bnrelu<<<25000, 256, 0, stream>>>((const uint4*)buf1, scale1, shift1, (uint4*)buf2);

    // layer 2 (transform-first; gemm epilogue prescales by dinv)
    k_gemm<256, 1, 4, 4, true><<<g64, 256, 0, stream>>>(buf2, w2s, dinv, (unsigned short*)buf1, NNODES, 256);
    k_aggb<<<NNODES / 4, 256, 0, stream>>>((const uint2*)buf1, offs, csr, dinv, (uint2*)buf2);
    k_stats<<<SB, 256, 0, stream>>>((const unsigned short*)buf2, sums2, sq2);
    k_bnparams<<<1, 256, 0, stream>>>(sums2, sq2, g2, be2, scale2, shift2);
    k_bnrelu<<<25000, 256, 0, stream>>>((const uint4*)buf2, scale2, shift2, (uint4*)buf1);

    // layer 3 (transform to 40 bf16 prescaled, aggregate + log_softmax fused)
    k_gemm<256, 4, 1, 3, true><<<dim3((NNODES + 255) / 256, 1), 256, 0, stream>>>(buf1, w3s, dinv, (unsigned short*)buf0, NNODES, 40);
    k_agg3<<<NNODES / 4, 256, 0, stream>>>((const unsigned*)buf0, offs, csr, dinv, b3, (float*)d_out);
}

// Round 5
// 1244.852 us; speedup vs baseline: 1.6389x; 1.6389x over previous
//
#include <hip/hip_runtime.h>
#include <hip/hip_bf16.h>

#define NNODES 200000
#define NEDGES 3200000
#define NBUCK 782            // ceil(NNODES/256)
#define NEB 512              // edge blocks for counting sort
#define EPB (NEDGES / NEB)   // 6250 edges per block
#define EPS 1e-5f

typedef __bf16 bf16x8 __attribute__((ext_vector_type(8)));
typedef float  f32x4  __attribute__((ext_vector_type(4)));

__device__ __forceinline__ float bflo(unsigned u) { return __uint_as_float(u << 16); }
__device__ __forceinline__ float bfhi(unsigned u) { return __uint_as_float(u & 0xffff0000u); }
__device__ __forceinline__ unsigned short f2b(float f) {
    return __builtin_bit_cast(unsigned short, __float2bfloat16(f));
}
__device__ __forceinline__ unsigned pk2(float a, float b) {
    return (unsigned)f2b(a) | ((unsigned)f2b(b) << 16);
}

// ---------------- CSR build: atomic-free two-level counting sort ----------------
// pass 1: per-block LDS histogram of buckets (bucket = row>>8)
__global__ __launch_bounds__(256) void k_cnt(const int* __restrict__ row, int* __restrict__ cnt) {
    __shared__ int h[NBUCK];
    for (int i = threadIdx.x; i < NBUCK; i += 256) h[i] = 0;
    __syncthreads();
    const int e0 = blockIdx.x * EPB;
    for (int i = e0 + threadIdx.x; i < e0 + EPB; i += 256)
        atomicAdd(&h[row[i] >> 8], 1);
    __syncthreads();
    for (int i = threadIdx.x; i < NBUCK; i += 256)
        cnt[(size_t)blockIdx.x * NBUCK + i] = h[i];
}

// pass 2: one wave per bucket — exclusive scan of its 512-block column; emit bucket total
__global__ __launch_bounds__(256) void k_bscan(int* __restrict__ cnt, int* __restrict__ btot) {
    const int wv = (blockIdx.x * 256 + threadIdx.x) >> 6;   // bucket
    const int lane = threadIdx.x & 63;
    if (wv >= NBUCK) return;
    int v[8]; int s = 0;
#pragma unroll
    for (int j = 0; j < 8; ++j) {
        v[j] = cnt[(size_t)(lane * 8 + j) * NBUCK + wv];
        s += v[j];
    }
    int excl = s;
#pragma unroll
    for (int o = 1; o < 64; o <<= 1) {
        int t = __shfl_up(excl, o);
        if (lane >= o) excl += t;
    }
    excl -= s;                                // exclusive prefix over blocks
    if (lane == 63) btot[wv] = excl + s;
    int base = excl;
#pragma unroll
    for (int j = 0; j < 8; ++j) {
        int t = v[j];
        cnt[(size_t)(lane * 8 + j) * NBUCK + wv] = base;   // bucket-relative base
        base += t;
    }
}

// pass 3: scan bucket totals -> bucket bases
__global__ __launch_bounds__(1024) void k_btscan(const int* __restrict__ btot, int* __restrict__ bbase) {
    __shared__ int s[1024];
    int t = threadIdx.x;
    int v = (t < NBUCK) ? btot[t] : 0;
    s[t] = v;
    __syncthreads();
    for (int off = 1; off < 1024; off <<= 1) {
        int u = (t >= off) ? s[t - off] : 0;
        __syncthreads();
        s[t] += u;
        __syncthreads();
    }
    if (t < NBUCK) bbase[t + 1] = s[t];
    if (t == 0) bbase[0] = 0;
}

// pass 4: place edges into bucket-major ebuf (LDS-atomic local ranks only)
__global__ __launch_bounds__(256) void k_place(const int* __restrict__ row, const int* __restrict__ col,
                                               const int* __restrict__ cnt, const int* __restrict__ bbase,
                                               unsigned* __restrict__ ebuf) {
    __shared__ int base[NBUCK];
    for (int i = threadIdx.x; i < NBUCK; i += 256)
        base[i] = bbase[i] + cnt[(size_t)blockIdx.x * NBUCK + i];
    __syncthreads();
    const int e0 = blockIdx.x * EPB;
    for (int i = e0 + threadIdx.x; i < e0 + EPB; i += 256) {
        int r = row[i], c = col[i];
        int p = atomicAdd(&base[r >> 8], 1);
        ebuf[p] = ((unsigned)(r & 255) << 18) | (unsigned)c;   // col < 2^18
    }
}

// pass 5: per-node degree from binned edges (replaces 3.2M-global-atomic k_hist)
__global__ __launch_bounds__(256) void k_ndeg(const unsigned* __restrict__ ebuf,
                                              const int* __restrict__ bbase,
                                              int* __restrict__ deg) {
    __shared__ int cnt[256];
    const int b = blockIdx.x;
    const int t = threadIdx.x;
    cnt[t] = 0;
    __syncthreads();
    const int s = bbase[b], e = bbase[b + 1];
    for (int i = s + t; i < e; i += 256)
        atomicAdd(&cnt[ebuf[i] >> 18], 1);
    __syncthreads();
    const int n0 = b * 256;
    if (n0 + t < NNODES) deg[n0 + t] = cnt[t];
}

__global__ __launch_bounds__(256) void k_scan1(const int* __restrict__ deg, int* __restrict__ offs,
                                               int* __restrict__ bsum, float* __restrict__ dinv) {
    __shared__ int s[256];
    int i = blockIdx.x * 256 + threadIdx.x;
    int d = 0;
    if (i < NNODES) {
        d = deg[i];                          // real edges only; self loop analytic
        dinv[i] = rsqrtf((float)(d + 1));
    }
    s[threadIdx.x] = d;
    __syncthreads();
    for (int off = 1; off < 256; off <<= 1) {
        int v = (threadIdx.x >= off) ? s[threadIdx.x - off] : 0;
        __syncthreads();
        s[threadIdx.x] += v;
        __syncthreads();
    }
    if (i < NNODES) offs[i + 1] = s[threadIdx.x];
    if (threadIdx.x == 255) bsum[blockIdx.x] = s[255];
    if (i == 0) offs[0] = 0;
}

__global__ __launch_bounds__(1024) void k_scan2(int* __restrict__ bsum, int nb) {
    __shared__ int s[1024];
    int t = threadIdx.x;
    int v = (t < nb) ? bsum[t] : 0;
    s[t] = v;
    __syncthreads();
    for (int off = 1; off < 1024; off <<= 1) {
        int u = (t >= off) ? s[t - off] : 0;
        __syncthreads();
        s[t] += u;
        __syncthreads();
    }
    if (t < nb) bsum[t] = s[t] - v;         // exclusive base
}

__global__ __launch_bounds__(256) void k_scan3(int* __restrict__ offs, const int* __restrict__ bsum) {
    int i = blockIdx.x * 256 + threadIdx.x;
    if (i < NNODES) offs[i + 1] += bsum[blockIdx.x];
}

// final: rank within bucket via LDS histogram, emit final CSR (bucket-local writes)
__global__ __launch_bounds__(256) void k_sort(const unsigned* __restrict__ ebuf,
                                              const int* __restrict__ offs,
                                              int* __restrict__ csr) {
    __shared__ int cnt[256];
    __shared__ int sofs[257];
    const int b = blockIdx.x;
    const int n0 = b * 256;
    const int t = threadIdx.x;
    const int nloc = min(256, NNODES - n0);
    cnt[t] = 0;
    sofs[t] = offs[min(n0 + t, NNODES)];
    if (t == 0) sofs[256] = offs[min(n0 + 256, NNODES)];
    __syncthreads();
    const int s = sofs[0], e = sofs[nloc];
    for (int i = s + t; i < e; i += 256) {
        unsigned v = ebuf[i];
        int nl = v >> 18;
        int rank = atomicAdd(&cnt[nl], 1);
        csr[sofs[nl] + rank] = (int)(v & 0x3FFFFu);
    }
}

// ---------------- cast x to bf16, prescaled by dinv ----------------
__global__ __launch_bounds__(256) void k_cast(const float* __restrict__ x,
                                              const float* __restrict__ dinv,
                                              uint4* __restrict__ xb) {
    size_t t = (size_t)blockIdx.x * 256 + threadIdx.x;   // one uint4 (8 bf16) per thread
    int n = (int)(t >> 4);                                // 16 threads per 128-feat row
    float d = dinv[n];
    const float4* xp = (const float4*)(x + t * 8);
    float4 a = xp[0], b = xp[1];
    uint4 o;
    o.x = pk2(a.x * d, a.y * d); o.y = pk2(a.z * d, a.w * d);
    o.z = pk2(b.x * d, b.y * d); o.w = pk2(b.z * d, b.w * d);
    xb[t] = o;
}

// ---------------- aggregation: bf16 prescaled, F=128 (layer 1) ----------------
__global__ __launch_bounds__(256) void k_aggf(const unsigned* __restrict__ xb,
                                              const int* __restrict__ offs,
                                              const int* __restrict__ csr,
                                              const float* __restrict__ dinv,
                                              unsigned* __restrict__ out) {
    const int lane = threadIdx.x & 63;
    const int node = blockIdx.x * 4 + (threadIdx.x >> 6);
    const unsigned* base = xb + lane;                     // row stride 64 uints
    unsigned us = base[(size_t)node * 64];
    float a0 = bflo(us), a1 = bfhi(us);                   // self term (prescaled)
    int p = offs[node];
    const int p1 = offs[node + 1];
    for (; p + 4 <= p1; p += 4) {
        int i0 = csr[p], i1 = csr[p + 1], i2 = csr[p + 2], i3 = csr[p + 3];
        unsigned u0 = base[(size_t)i0 * 64];
        unsigned u1 = base[(size_t)i1 * 64];
        unsigned u2 = base[(size_t)i2 * 64];
        unsigned u3 = base[(size_t)i3 * 64];
        a0 += bflo(u0) + bflo(u1) + bflo(u2) + bflo(u3);
        a1 += bfhi(u0) + bfhi(u1) + bfhi(u2) + bfhi(u3);
    }
    for (; p < p1; ++p) {
        unsigned u0 = base[(size_t)csr[p] * 64];
        a0 += bflo(u0); a1 += bfhi(u0);
    }
    const float d = dinv[node];
    out[(size_t)node * 64 + lane] = pk2(a0 * d, a1 * d);
}

// ---------------- aggregation: bf16 prescaled, F=256 (layer 2) ----------------
__global__ __launch_bounds__(256) void k_aggb(const uint2* __restrict__ in,
                                              const int* __restrict__ offs,
                                              const int* __restrict__ csr,
                                              const float* __restrict__ dinv,
                                              uint2* __restrict__ out) {
    const int lane = threadIdx.x & 63;
    const int node = blockIdx.x * 4 + (threadIdx.x >> 6);
    const uint2* base = in + lane;                        // row stride 64 uint2
    uint2 us = base[(size_t)node * 64];
    float a0 = bflo(us.x), a1 = bfhi(us.x), a2 = bflo(us.y), a3 = bfhi(us.y);
    int p = offs[node];
    const int p1 = offs[node + 1];
    for (; p + 4 <= p1; p += 4) {
        int i0 = csr[p], i1 = csr[p + 1], i2 = csr[p + 2], i3 = csr[p + 3];
        uint2 u0 = base[(size_t)i0 * 64];
        uint2 u1 = base[(size_t)i1 * 64];
        uint2 u2 = base[(size_t)i2 * 64];
        uint2 u3 = base[(size_t)i3 * 64];
        a0 += bflo(u0.x) + bflo(u1.x) + bflo(u2.x) + bflo(u3.x);
        a1 += bfhi(u0.x) + bfhi(u1.x) + bfhi(u2.x) + bfhi(u3.x);
        a2 += bflo(u0.y) + bflo(u1.y) + bflo(u2.y) + bflo(u3.y);
        a3 += bfhi(u0.y) + bfhi(u1.y) + bfhi(u2.y) + bfhi(u3.y);
    }
    for (; p < p1; ++p) {
        uint2 u0 = base[(size_t)csr[p] * 64];
        a0 += bflo(u0.x); a1 += bfhi(u0.x); a2 += bflo(u0.y); a3 += bfhi(u0.y);
    }
    const float d = dinv[node];
    uint2 o;
    o.x = pk2(a0 * d, a1 * d);
    o.y = pk2(a2 * d, a3 * d);
    out[(size_t)node * 64 + lane] = o;
}

// final layer: aggregate 40 bf16 prescaled feats, 3 edges/iter, + b3 + log_softmax
__global__ __launch_bounds__(256) void k_agg3(const unsigned* __restrict__ T3b,
                                              const int* __restrict__ offs,
                                              const int* __restrict__ csr,
                                              const float* __restrict__ dinv,
                                              const float* __restrict__ b3,
                                              float* __restrict__ out) {
    const int lane = threadIdx.x & 63;
    const int node = blockIdx.x * 4 + (threadIdx.x >> 6);
    const int grp = lane / 20;            // 0,1,2 (lanes 60-63 idle)
    const int f2 = lane - grp * 20;       // feat pair index
    const bool act = lane < 60;
    const unsigned* base = T3b + f2;      // row stride 20 uints
    float a0 = 0.f, a1 = 0.f;
    const int p1 = offs[node + 1];
    int q = offs[node] + grp;
    if (act) {
        if (grp == 0) {                   // self term
            unsigned u = base[(size_t)node * 20];
            a0 = bflo(u); a1 = bfhi(u);
        }
        while (q + 3 < p1) {
            int i0 = csr[q], i1 = csr[q + 3];
            unsigned u0 = base[(size_t)i0 * 20];
            unsigned u1 = base[(size_t)i1 * 20];
            a0 += bflo(u0) + bflo(u1);
            a1 += bfhi(u0) + bfhi(u1);
            q += 6;
        }
        if (q < p1) {
            unsigned u0 = base[(size_t)csr[q] * 20];
            a0 += bflo(u0); a1 += bfhi(u0);
        }
    }
    // reduce across the 3 lane groups (valid for lanes 0-19)
    float t0 = __shfl(a0, (lane + 20) & 63), t1 = __shfl(a0, (lane + 40) & 63);
    float s0 = __shfl(a1, (lane + 20) & 63), s1 = __shfl(a1, (lane + 40) & 63);
    a0 += t0 + t1;
    a1 += s0 + s1;
    const bool ok = lane < 20;
    const float d = dinv[node];
    float2 bb = ok ? *(const float2*)(b3 + 2 * f2) : make_float2(0.f, 0.f);
    float v0 = a0 * d + bb.x;
    float v1 = a1 * d + bb.y;
    float m = ok ? fmaxf(v0, v1) : -INFINITY;
#pragma unroll
    for (int o = 16; o >= 1; o >>= 1) m = fmaxf(m, __shfl_xor(m, o));
    float e = ok ? (__expf(v0 - m) + __expf(v1 - m)) : 0.f;
    float s = e;
#pragma unroll
    for (int o = 16; o >= 1; o >>= 1) s += __shfl_xor(s, o);
    float ls = __logf(s);
    if (ok) {
        float2 r = make_float2(v0 - m - ls, v1 - m - ls);
        *(float2*)(out + (size_t)node * 40 + 2 * f2) = r;
    }
}

// ---------------- W pre-swizzle (fp32 -> bf16 MFMA b-frag order) ----------------
__global__ __launch_bounds__(256) void k_prepw(const float* __restrict__ W,
                                               __hip_bfloat16* __restrict__ Wswz,
                                               int K, int NOUT, int NFRAG) {
    int t = blockIdx.x * 256 + threadIdx.x;
    int KSTEPS = K / 32;
    if (t >= NFRAG * KSTEPS * 64) return;
    int lane = t & 63;
    int ks = (t >> 6) % KSTEPS;
    int g  = (t >> 6) / KSTEPS;
    int c = lane & 15, q = lane >> 4;
    int col = g * 16 + c;
    int k0 = ks * 32 + q * 8;
    unsigned short vals[8];
#pragma unroll
    for (int j = 0; j < 8; ++j)
        vals[j] = (col < NOUT) ? f2b(W[(size_t)(k0 + j) * NOUT + col]) : (unsigned short)0;
    *(uint4*)((char*)Wswz + (size_t)t * 16) = __builtin_bit_cast(uint4, vals);
}

// ---------------- MFMA GEMM: C[M x NOUT] = A[M x K] @ W, optional dinv prescale ----------------
template <int K, int MW, int NW, int WNB, bool PRESCALE>
__global__ __launch_bounds__(MW * NW * 64) void k_gemm(const __hip_bfloat16* __restrict__ A,
                                                       const __hip_bfloat16* __restrict__ Wswz,
                                                       const float* __restrict__ dinvp,
                                                       unsigned short* __restrict__ Cout,
                                                       int M, int NOUT) {
    constexpr int KSTEPS = K / 32;
    const int lane = threadIdx.x & 63;
    const int wid  = threadIdx.x >> 6;
    const int wm = (wid % MW) * 64;
    const int wn = (wid / MW) * (WNB * 16);
    const long rowBase = (long)blockIdx.x * (MW * 64);
    const int cl = lane & 15, q = lane >> 4;

    const __hip_bfloat16* aptr[4];
#pragma unroll
    for (int mf = 0; mf < 4; ++mf) {
        long r = rowBase + wm + mf * 16 + cl;
        if (r > M - 1) r = M - 1;           // tail clamp (stores predicated)
        aptr[mf] = A + r * K + q * 8;
    }
    const __hip_bfloat16* bptr[WNB];
#pragma unroll
    for (int nf = 0; nf < WNB; ++nf) {
        int g = wn / 16 + nf;
        bptr[nf] = Wswz + (size_t)g * KSTEPS * 512 + (size_t)lane * 8;
    }

    f32x4 acc[4][WNB];
    const f32x4 z = {0.f, 0.f, 0.f, 0.f};
#pragma unroll
    for (int mf = 0; mf < 4; ++mf)
#pragma unroll
        for (int nf = 0; nf < WNB; ++nf) acc[mf][nf] = z;

#pragma unroll
    for (int ks = 0; ks < KSTEPS; ++ks) {
        bf16x8 a[4], b[WNB];
#pragma unroll
        for (int mf = 0; mf < 4; ++mf)
            a[mf] = __builtin_bit_cast(bf16x8, *(const uint4*)(aptr[mf] + ks * 32));
#pragma unroll
        for (int nf = 0; nf < WNB; ++nf)
            b[nf] = __builtin_bit_cast(bf16x8, *(const uint4*)(bptr[nf] + ks * 512));
#pragma unroll
        for (int mf = 0; mf < 4; ++mf)
#pragma unroll
            for (int nf = 0; nf < WNB; ++nf)
                acc[mf][nf] = __builtin_amdgcn_mfma_f32_16x16x32_bf16(a[mf], b[nf], acc[mf][nf], 0, 0, 0);
    }

#pragma unroll
    for (int mf = 0; mf < 4; ++mf)
#pragma unroll
        for (int i = 0; i < 4; ++i) {
            long row = rowBase + wm + mf * 16 + q * 4 + i;
            if (row >= M) continue;
            float dv = PRESCALE ? dinvp[row] : 1.0f;
#pragma unroll
            for (int nf = 0; nf < WNB; ++nf) {
                int col = wn + nf * 16 + cl;
                if (col < NOUT)
                    Cout[row * NOUT + col] = f2b(PRESCALE ? acc[mf][nf][i] * dv : acc[mf][nf][i]);
            }
        }
}

// ---------------- BN stats / params / apply ----------------
__global__ __launch_bounds__(256) void k_stats(const unsigned short* __restrict__ Zu,
                                               float* __restrict__ sums, float* __restrict__ sq) {
    const int t = threadIdx.x;
    const long r0 = (long)blockIdx.x * 256;
    float s = 0.f, s2 = 0.f;
    for (int i = 0; i < 256; ++i) {
        long r = r0 + i;
        if (r >= NNODES) break;
        float v = __uint_as_float((unsigned)Zu[r * 256 + t] << 16);
        s += v; s2 += v * v;
    }
    atomicAdd(&sums[t], s);
    atomicAdd(&sq[t], s2);
}

__global__ __launch_bounds__(256) void k_bnparams(const float* __restrict__ sums, const float* __restrict__ sq,
                                                  const float* __restrict__ gamma,
                                                  const float* __restrict__ beta,
                                                  float* __restrict__ scale, float* __restrict__ shift) {
    int t = threadIdx.x;
    float mu = sums[t] * (1.0f / NNODES);
    float var = sq[t] * (1.0f / NNODES) - mu * mu;
    if (var < 0.f) var = 0.f;
    float sc = gamma[t] * rsqrtf(var + EPS);
    scale[t] = sc;
    shift[t] = beta[t] - mu * sc;
}

__global__ __launch_bounds__(256) void k_bnrelu(const uint4* __restrict__ Z,
                                                const float* __restrict__ scale,
                                                const float* __restrict__ shift,
                                                uint4* __restrict__ H) {
    size_t t = (size_t)blockIdx.x * 256 + threadIdx.x;
    uint4 u = Z[t];
    int c0 = (int)((t * 8) & 255);
    float v[8] = {bflo(u.x), bfhi(u.x), bflo(u.y), bfhi(u.y),
                  bflo(u.z), bfhi(u.z), bflo(u.w), bfhi(u.w)};
    float r[8];
#pragma unroll
    for (int j = 0; j < 8; ++j) r[j] = fmaxf(0.f, v[j] * scale[c0 + j] + shift[c0 + j]);
    uint4 o;
    o.x = pk2(r[0], r[1]); o.y = pk2(r[2], r[3]); o.z = pk2(r[4], r[5]); o.w = pk2(r[6], r[7]);
    H[t] = o;
}

// ---------------- driver ----------------
extern "C" void kernel_launch(void* const* d_in, const int* in_sizes, int n_in,
                              void* d_out, int out_size, void* d_ws, size_t ws_size,
                              hipStream_t stream) {
    const float* x   = (const float*)d_in[0];
    const int*   ei  = (const int*)d_in[1];
    const float* W1  = (const float*)d_in[2];
    const float* g1  = (const float*)d_in[4];
    const float* be1 = (const float*)d_in[5];
    const float* W2  = (const float*)d_in[6];
    const float* g2  = (const float*)d_in[8];
    const float* be2 = (const float*)d_in[9];
    const float* W3  = (const float*)d_in[10];
    const float* b3  = (const float*)d_in[11];
    // b1 (d_in[3]) and b2 (d_in[7]) cancel exactly under BatchNorm — skipped.

    char* w = (char*)d_ws;
    size_t o = 0;
    auto alloc = [&](size_t b) { size_t r = o; o += (b + 255) & ~(size_t)255; return r; };
    int*   deg  = (int*)(w + alloc((size_t)NNODES * 4));
    int*   offs = (int*)(w + alloc((size_t)(NNODES + 1) * 4));
    float* dinv = (float*)(w + alloc((size_t)NNODES * 4));
    int*   bsum = (int*)(w + alloc(1024 * 4));
    int*   cnt  = (int*)(w + alloc((size_t)NEB * NBUCK * 4));   // 1.6 MB
    int*   btot = (int*)(w + alloc(NBUCK * 4));
    int*   bbase= (int*)(w + alloc((NBUCK + 1) * 4));
    unsigned* ebuf = (unsigned*)(w + alloc((size_t)NEDGES * 4));
    int*   csr  = (int*)(w + alloc((size_t)NEDGES * 4));
    float* stats = (float*)(w + alloc(4 * 256 * 4));   // sums1,sq1,sums2,sq2
    float* bnp   = (float*)(w + alloc(4 * 256 * 4));   // scale1,shift1,scale2,shift2
    __hip_bfloat16* w1s  = (__hip_bfloat16*)(w + alloc(65536));
    __hip_bfloat16* w2s  = (__hip_bfloat16*)(w + alloc(131072));
    __hip_bfloat16* w3s  = (__hip_bfloat16*)(w + alloc(24576));
    __hip_bfloat16* xb   = (__hip_bfloat16*)(w + alloc((size_t)NNODES * 128 * 2)); // x bf16 prescaled
    __hip_bfloat16* buf0 = (__hip_bfloat16*)(w + alloc((size_t)NNODES * 128 * 2)); // y0, later T3' bf16
    __hip_bfloat16* buf1 = (__hip_bfloat16*)(w + alloc((size_t)NNODES * 256 * 2)); // Z1 -> Z2' -> h2
    __hip_bfloat16* buf2 = (__hip_bfloat16*)(w + alloc((size_t)NNODES * 256 * 2)); // h1 -> y2

    float* sums1 = stats;       float* sq1 = stats + 256;
    float* sums2 = stats + 512; float* sq2 = stats + 768;
    float* scale1 = bnp;        float* shift1 = bnp + 256;
    float* scale2 = bnp + 512;  float* shift2 = bnp + 768;

    hipMemsetAsync(stats, 0, 4 * 256 * 4, stream);

    const int SB = (NNODES + 255) / 256;  // 782
    // CSR build (no global atomics)
    k_cnt<<<NEB, 256, 0, stream>>>(ei, cnt);
    k_bscan<<<(NBUCK * 64 + 255) / 256, 256, 0, stream>>>(cnt, btot);
    k_btscan<<<1, 1024, 0, stream>>>(btot, bbase);
    k_place<<<NEB, 256, 0, stream>>>(ei, ei + NEDGES, cnt, bbase, ebuf);
    k_ndeg<<<NBUCK, 256, 0, stream>>>(ebuf, bbase, deg);
    k_scan1<<<SB, 256, 0, stream>>>(deg, offs, bsum, dinv);
    k_scan2<<<1, 1024, 0, stream>>>(bsum, SB);
    k_scan3<<<SB, 256, 0, stream>>>(offs, bsum);
    k_sort<<<NBUCK, 256, 0, stream>>>(ebuf, offs, csr);
    k_cast<<<(NNODES * 128 / 8) / 256, 256, 0, stream>>>(x, dinv, (uint4*)xb);

    k_prepw<<<16, 256, 0, stream>>>(W1, w1s, 128, 256, 16);
    k_prepw<<<32, 256, 0, stream>>>(W2, w2s, 256, 256, 16);
    k_prepw<<<6, 256, 0, stream>>>(W3, w3s, 256, 40, 3);

    const dim3 g64((NNODES + 63) / 64, 1);   // 3125, 64-row blocks

    // layer 1 (aggregate-first on prescaled bf16 x)
    k_aggf<<<NNODES / 4, 256, 0, stream>>>((const unsigned*)xb, offs, csr, dinv, (unsigned*)buf0);
    k_gemm<128, 1, 4, 4, false><<<g64, 256, 0, stream>>>(buf0, w1s, nullptr, (unsigned short*)buf1, NNODES, 256);
    k_stats<<<SB, 256, 0, stream>>>((const unsigned short*)buf1, sums1, sq1);
    k_bnparams<<<1, 256, 0, stream>>>(sums1, sq1, g1, be1, scale1, shift1);
    k_bnrelu<<<25000, 256, 0, stream>>>((const uint4*)buf1, scale1, shift1, (uint4*)buf2);

    // layer 2 (transform-first; gemm epilogue prescales by dinv)
    k_gemm<256, 1, 4, 4, true><<<g64, 256, 0, stream>>>(buf2, w2s, dinv, (unsigned short*)buf1, NNODES, 256);
    k_aggb<<<NNODES / 4, 256, 0, stream>>>((const uint2*)buf1, offs, csr, dinv, (uint2*)buf2);
    k_stats<<<SB, 256, 0, stream>>>((const unsigned short*)buf2, sums2, sq2);
    k_bnparams<<<1, 256, 0, stream>>>(sums2, sq2, g2, be2, scale2, shift2);
    k_bnrelu<<<25000, 256, 0, stream>>>((const uint4*)buf2, scale2, shift2, (uint4*)buf1);

    // layer 3 (transform to 40 bf16 prescaled, aggregate + log_softmax fused)
    k_gemm<256, 4, 1, 3, true><<<dim3((NNODES + 255) / 256, 1), 256, 0, stream>>>(buf1, w3s, dinv, (unsigned short*)buf0, NNODES, 40);
    k_agg3<<<NNODES / 4, 256, 0, stream>>>((const unsigned*)buf0, offs, csr, dinv, b3, (float*)d_out);
}

// Round 6
// 1219.364 us; speedup vs baseline: 1.6731x; 1.0209x over previous
//
#include <hip/hip_runtime.h>
#include <hip/hip_bf16.h>

#define NNODES 200000
#define NEDGES 3200000
#define NBUCK 782            // ceil(NNODES/256)
#define NEB 512              // edge blocks for counting sort
#define EPB (NEDGES / NEB)   // 6250 edges per block
#define EPS 1e-5f

typedef __bf16 bf16x8 __attribute__((ext_vector_type(8)));
typedef float  f32x4  __attribute__((ext_vector_type(4)));

__device__ __forceinline__ float bflo(unsigned u) { return __uint_as_float(u << 16); }
__device__ __forceinline__ float bfhi(unsigned u) { return __uint_as_float(u & 0xffff0000u); }
__device__ __forceinline__ unsigned short f2b(float f) {
    return __builtin_bit_cast(unsigned short, __float2bfloat16(f));
}
__device__ __forceinline__ unsigned pk2(float a, float b) {
    return (unsigned)f2b(a) | ((unsigned)f2b(b) << 16);
}

// ---------------- CSR build: atomic-free two-level counting sort ----------------
__global__ __launch_bounds__(256) void k_cnt(const int* __restrict__ row, int* __restrict__ cnt) {
    __shared__ int h[NBUCK];
    for (int i = threadIdx.x; i < NBUCK; i += 256) h[i] = 0;
    __syncthreads();
    const int e0 = blockIdx.x * EPB;
    for (int i = e0 + threadIdx.x; i < e0 + EPB; i += 256)
        atomicAdd(&h[row[i] >> 8], 1);
    __syncthreads();
    for (int i = threadIdx.x; i < NBUCK; i += 256)
        cnt[(size_t)blockIdx.x * NBUCK + i] = h[i];
}

__global__ __launch_bounds__(256) void k_bscan(int* __restrict__ cnt, int* __restrict__ btot) {
    const int wv = (blockIdx.x * 256 + threadIdx.x) >> 6;   // bucket
    const int lane = threadIdx.x & 63;
    if (wv >= NBUCK) return;
    int v[8]; int s = 0;
#pragma unroll
    for (int j = 0; j < 8; ++j) {
        v[j] = cnt[(size_t)(lane * 8 + j) * NBUCK + wv];
        s += v[j];
    }
    int excl = s;
#pragma unroll
    for (int o = 1; o < 64; o <<= 1) {
        int t = __shfl_up(excl, o);
        if (lane >= o) excl += t;
    }
    excl -= s;
    if (lane == 63) btot[wv] = excl + s;
    int base = excl;
#pragma unroll
    for (int j = 0; j < 8; ++j) {
        int t = v[j];
        cnt[(size_t)(lane * 8 + j) * NBUCK + wv] = base;
        base += t;
    }
}

__global__ __launch_bounds__(1024) void k_btscan(const int* __restrict__ btot, int* __restrict__ bbase) {
    __shared__ int s[1024];
    int t = threadIdx.x;
    int v = (t < NBUCK) ? btot[t] : 0;
    s[t] = v;
    __syncthreads();
    for (int off = 1; off < 1024; off <<= 1) {
        int u = (t >= off) ? s[t - off] : 0;
        __syncthreads();
        s[t] += u;
        __syncthreads();
    }
    if (t < NBUCK) bbase[t + 1] = s[t];
    if (t == 0) bbase[0] = 0;
}

__global__ __launch_bounds__(256) void k_place(const int* __restrict__ row, const int* __restrict__ col,
                                               const int* __restrict__ cnt, const int* __restrict__ bbase,
                                               unsigned* __restrict__ ebuf) {
    __shared__ int base[NBUCK];
    for (int i = threadIdx.x; i < NBUCK; i += 256)
        base[i] = bbase[i] + cnt[(size_t)blockIdx.x * NBUCK + i];
    __syncthreads();
    const int e0 = blockIdx.x * EPB;
    for (int i = e0 + threadIdx.x; i < e0 + EPB; i += 256) {
        int r = row[i], c = col[i];
        int p = atomicAdd(&base[r >> 8], 1);
        ebuf[p] = ((unsigned)(r & 255) << 18) | (unsigned)c;   // col < 2^18
    }
}

__global__ __launch_bounds__(256) void k_ndeg(const unsigned* __restrict__ ebuf,
                                              const int* __restrict__ bbase,
                                              int* __restrict__ deg) {
    __shared__ int cnt[256];
    const int b = blockIdx.x;
    const int t = threadIdx.x;
    cnt[t] = 0;
    __syncthreads();
    const int s = bbase[b], e = bbase[b + 1];
    for (int i = s + t; i < e; i += 256)
        atomicAdd(&cnt[ebuf[i] >> 18], 1);
    __syncthreads();
    const int n0 = b * 256;
    if (n0 + t < NNODES) deg[n0 + t] = cnt[t];
}

__global__ __launch_bounds__(256) void k_scan1(const int* __restrict__ deg, int* __restrict__ offs,
                                               int* __restrict__ bsum, float* __restrict__ dinv) {
    __shared__ int s[256];
    int i = blockIdx.x * 256 + threadIdx.x;
    int d = 0;
    if (i < NNODES) {
        d = deg[i];
        dinv[i] = rsqrtf((float)(d + 1));
    }
    s[threadIdx.x] = d;
    __syncthreads();
    for (int off = 1; off < 256; off <<= 1) {
        int v = (threadIdx.x >= off) ? s[threadIdx.x - off] : 0;
        __syncthreads();
        s[threadIdx.x] += v;
        __syncthreads();
    }
    if (i < NNODES) offs[i + 1] = s[threadIdx.x];
    if (threadIdx.x == 255) bsum[blockIdx.x] = s[255];
    if (i == 0) offs[0] = 0;
}

__global__ __launch_bounds__(1024) void k_scan2(int* __restrict__ bsum, int nb) {
    __shared__ int s[1024];
    int t = threadIdx.x;
    int v = (t < nb) ? bsum[t] : 0;
    s[t] = v;
    __syncthreads();
    for (int off = 1; off < 1024; off <<= 1) {
        int u = (t >= off) ? s[t - off] : 0;
        __syncthreads();
        s[t] += u;
        __syncthreads();
    }
    if (t < nb) bsum[t] = s[t] - v;
}

__global__ __launch_bounds__(256) void k_scan3(int* __restrict__ offs, const int* __restrict__ bsum) {
    int i = blockIdx.x * 256 + threadIdx.x;
    if (i < NNODES) offs[i + 1] += bsum[blockIdx.x];
}

__global__ __launch_bounds__(256) void k_sort(const unsigned* __restrict__ ebuf,
                                              const int* __restrict__ offs,
                                              int* __restrict__ csr) {
    __shared__ int cnt[256];
    __shared__ int sofs[257];
    const int b = blockIdx.x;
    const int n0 = b * 256;
    const int t = threadIdx.x;
    const int nloc = min(256, NNODES - n0);
    cnt[t] = 0;
    sofs[t] = offs[min(n0 + t, NNODES)];
    if (t == 0) sofs[256] = offs[min(n0 + 256, NNODES)];
    __syncthreads();
    const int s = sofs[0], e = sofs[nloc];
    for (int i = s + t; i < e; i += 256) {
        unsigned v = ebuf[i];
        int nl = v >> 18;
        int rank = atomicAdd(&cnt[nl], 1);
        csr[sofs[nl] + rank] = (int)(v & 0x3FFFFu);
    }
}

// ---------------- cast x to bf16, prescaled by dinv ----------------
__global__ __launch_bounds__(256) void k_cast(const float* __restrict__ x,
                                              const float* __restrict__ dinv,
                                              uint4* __restrict__ xb) {
    size_t t = (size_t)blockIdx.x * 256 + threadIdx.x;
    int n = (int)(t >> 4);
    float d = dinv[n];
    const float4* xp = (const float4*)(x + t * 8);
    float4 a = xp[0], b = xp[1];
    uint4 o;
    o.x = pk2(a.x * d, a.y * d); o.y = pk2(a.z * d, a.w * d);
    o.z = pk2(b.x * d, b.y * d); o.w = pk2(b.z * d, b.w * d);
    xb[t] = o;
}

// ---------------- aggregation: F=128 rows (16 x uint4), 4 edges per load ----------------
__global__ __launch_bounds__(256) void k_aggf(const uint4* __restrict__ in,
                                              const int* __restrict__ offs,
                                              const int* __restrict__ csr,
                                              const float* __restrict__ dinv,
                                              uint4* __restrict__ out) {
    const int lane = threadIdx.x & 63;
    const int grp = lane >> 4;          // 0..3 : which item of the quad
    const int fl = lane & 15;           // 16B chunk within row
    const int node = blockIdx.x * 4 + (threadIdx.x >> 6);
    const int p0 = offs[node];
    const int K = offs[node + 1] - p0 + 1;   // +1 virtual self item at k=0
    float a0=0,a1=0,a2=0,a3=0,a4=0,a5=0,a6=0,a7=0;
    auto accum = [&](uint4 u) {
        a0 += bflo(u.x); a1 += bfhi(u.x);
        a2 += bflo(u.y); a3 += bfhi(u.y);
        a4 += bflo(u.z); a5 += bfhi(u.z);
        a6 += bflo(u.w); a7 += bfhi(u.w);
    };
    int k = 0;
    for (; k + 8 <= K; k += 8) {
        int j0 = k + grp, j1 = k + 4 + grp;
        int i0 = (j0 == 0) ? node : csr[p0 + j0 - 1];
        int i1 = csr[p0 + j1 - 1];          // j1 >= 4 > 0 always
        uint4 u0 = in[(size_t)i0 * 16 + fl];
        uint4 u1 = in[(size_t)i1 * 16 + fl];
        accum(u0); accum(u1);
    }
    for (; k + 4 <= K; k += 4) {
        int j0 = k + grp;
        int i0 = (j0 == 0) ? node : csr[p0 + j0 - 1];
        accum(in[(size_t)i0 * 16 + fl]);
    }
    int rem = K - k;
    if (grp < rem) {
        int j0 = k + grp;
        int i0 = (j0 == 0) ? node : csr[p0 + j0 - 1];
        accum(in[(size_t)i0 * 16 + fl]);
    }
    // combine the 4 groups
#define RED(v) v += __shfl_xor(v, 32); v += __shfl_xor(v, 16);
    RED(a0) RED(a1) RED(a2) RED(a3) RED(a4) RED(a5) RED(a6) RED(a7)
#undef RED
    if (grp == 0) {
        const float d = dinv[node];
        uint4 o;
        o.x = pk2(a0 * d, a1 * d); o.y = pk2(a2 * d, a3 * d);
        o.z = pk2(a4 * d, a5 * d); o.w = pk2(a6 * d, a7 * d);
        out[(size_t)node * 16 + fl] = o;
    }
}

// ---------------- aggregation: F=256 rows (32 x uint4), 2 edges per load, unroll 4 ----------------
__global__ __launch_bounds__(256) void k_aggb(const uint4* __restrict__ in,
                                              const int* __restrict__ offs,
                                              const int* __restrict__ csr,
                                              const float* __restrict__ dinv,
                                              uint4* __restrict__ out) {
    const int lane = threadIdx.x & 63;
    const int half = lane >> 5;         // 0..1 : which item of the pair
    const int fl = lane & 31;           // 16B chunk within row
    const int node = blockIdx.x * 4 + (threadIdx.x >> 6);
    const int p0 = offs[node];
    const int K = offs[node + 1] - p0 + 1;
    float a0=0,a1=0,a2=0,a3=0,a4=0,a5=0,a6=0,a7=0;
    auto accum = [&](uint4 u) {
        a0 += bflo(u.x); a1 += bfhi(u.x);
        a2 += bflo(u.y); a3 += bfhi(u.y);
        a4 += bflo(u.z); a5 += bfhi(u.z);
        a6 += bflo(u.w); a7 += bfhi(u.w);
    };
    auto idxAt = [&](int j) -> int { return (j == 0) ? node : csr[p0 + j - 1]; };
    int k = 0;
    for (; k + 8 <= K; k += 8) {
        int i0 = idxAt(k + half);
        int i1 = csr[p0 + k + 1 + half];    // k+2+half - 1, always >= 1
        int i2 = csr[p0 + k + 3 + half];
        int i3 = csr[p0 + k + 5 + half];
        uint4 u0 = in[(size_t)i0 * 32 + fl];
        uint4 u1 = in[(size_t)i1 * 32 + fl];
        uint4 u2 = in[(size_t)i2 * 32 + fl];
        uint4 u3 = in[(size_t)i3 * 32 + fl];
        accum(u0); accum(u1); accum(u2); accum(u3);
    }
    for (; k + 2 <= K; k += 2) {
        accum(in[(size_t)idxAt(k + half) * 32 + fl]);
    }
    if (k < K && half == 0) {
        accum(in[(size_t)idxAt(k) * 32 + fl]);
    }
#define RED(v) v += __shfl_xor(v, 32);
    RED(a0) RED(a1) RED(a2) RED(a3) RED(a4) RED(a5) RED(a6) RED(a7)
#undef RED
    if (half == 0) {
        const float d = dinv[node];
        uint4 o;
        o.x = pk2(a0 * d, a1 * d); o.y = pk2(a2 * d, a3 * d);
        o.z = pk2(a4 * d, a5 * d); o.w = pk2(a6 * d, a7 * d);
        out[(size_t)node * 32 + fl] = o;
    }
}

// ---------------- final layer: 40-feat rows (5 x uint4), 12 edges per load + log_softmax ----------------
__global__ __launch_bounds__(256) void k_agg3(const uint4* __restrict__ T3b,
                                              const int* __restrict__ offs,
                                              const int* __restrict__ csr,
                                              const float* __restrict__ dinv,
                                              const float* __restrict__ b3,
                                              float* __restrict__ out) {
    const int lane = threadIdx.x & 63;
    const int grp = lane / 5;           // 0..12 (grp 12 = lanes 60-63, idle)
    const int fl = lane - grp * 5;      // 16B chunk within 80B row
    const bool act = grp < 12;
    const int node = blockIdx.x * 4 + (threadIdx.x >> 6);
    const int p0 = offs[node];
    const int K = offs[node + 1] - p0 + 1;
    float a0=0,a1=0,a2=0,a3=0,a4=0,a5=0,a6=0,a7=0;
    auto accum = [&](uint4 u) {
        a0 += bflo(u.x); a1 += bfhi(u.x);
        a2 += bflo(u.y); a3 += bfhi(u.y);
        a4 += bflo(u.z); a5 += bfhi(u.z);
        a6 += bflo(u.w); a7 += bfhi(u.w);
    };
    const char* Tb = (const char*)T3b;
    int k = 0;
    if (act) {
        for (; k + 12 <= K; k += 12) {
            int j = k + grp;
            int i0 = (j == 0) ? node : csr[p0 + j - 1];
            accum(*(const uint4*)(Tb + (size_t)i0 * 80 + fl * 16));
        }
        int rem = K - k;
        if (grp < rem) {
            int j = k + grp;
            int i0 = (j == 0) ? node : csr[p0 + j - 1];
            accum(*(const uint4*)(Tb + (size_t)i0 * 80 + fl * 16));
        }
    }
    // reduce 12 groups -> group 0 (lanes 0-4); lane stride between groups is 5
#define RED3(v) { float t = __shfl(v, lane + 30); v += t; t = __shfl(v, lane + 15); v += t; \
                  float u1 = __shfl(v, lane + 5); float u2 = __shfl(v, lane + 10); v += u1 + u2; }
    RED3(a0) RED3(a1) RED3(a2) RED3(a3) RED3(a4) RED3(a5) RED3(a6) RED3(a7)
#undef RED3
    const float d = dinv[node];
    float v[8];
    if (grp == 0) {
        const float4* bp = (const float4*)(b3 + fl * 8);
        float4 b01 = bp[0], b23 = bp[1];
        v[0] = a0 * d + b01.x; v[1] = a1 * d + b01.y;
        v[2] = a2 * d + b01.z; v[3] = a3 * d + b01.w;
        v[4] = a4 * d + b23.x; v[5] = a5 * d + b23.y;
        v[6] = a6 * d + b23.z; v[7] = a7 * d + b23.w;
    } else {
#pragma unroll
        for (int j = 0; j < 8; ++j) v[j] = -INFINITY;
    }
    float m = v[0];
#pragma unroll
    for (int j = 1; j < 8; ++j) m = fmaxf(m, v[j]);
    float mm = __shfl(m, 0);
#pragma unroll
    for (int l = 1; l < 5; ++l) mm = fmaxf(mm, __shfl(m, l));
    float e = 0.f;
    if (grp == 0) {
#pragma unroll
        for (int j = 0; j < 8; ++j) e += __expf(v[j] - mm);
    }
    float s = __shfl(e, 0);
#pragma unroll
    for (int l = 1; l < 5; ++l) s += __shfl(e, l);
    float ls = __logf(s);
    if (grp == 0) {
        float* op = out + (size_t)node * 40 + fl * 8;
        float4 o0 = {v[0] - mm - ls, v[1] - mm - ls, v[2] - mm - ls, v[3] - mm - ls};
        float4 o1 = {v[4] - mm - ls, v[5] - mm - ls, v[6] - mm - ls, v[7] - mm - ls};
        *(float4*)op = o0;
        *(float4*)(op + 4) = o1;
    }
}

// ---------------- W pre-swizzle (fp32 -> bf16 MFMA b-frag order) ----------------
__global__ __launch_bounds__(256) void k_prepw(const float* __restrict__ W,
                                               __hip_bfloat16* __restrict__ Wswz,
                                               int K, int NOUT, int NFRAG) {
    int t = blockIdx.x * 256 + threadIdx.x;
    int KSTEPS = K / 32;
    if (t >= NFRAG * KSTEPS * 64) return;
    int lane = t & 63;
    int ks = (t >> 6) % KSTEPS;
    int g  = (t >> 6) / KSTEPS;
    int c = lane & 15, q = lane >> 4;
    int col = g * 16 + c;
    int k0 = ks * 32 + q * 8;
    unsigned short vals[8];
#pragma unroll
    for (int j = 0; j < 8; ++j)
        vals[j] = (col < NOUT) ? f2b(W[(size_t)(k0 + j) * NOUT + col]) : (unsigned short)0;
    *(uint4*)((char*)Wswz + (size_t)t * 16) = __builtin_bit_cast(uint4, vals);
}

// ---------------- MFMA GEMM: C[M x NOUT] = A[M x K] @ W, optional dinv prescale ----------------
template <int K, int MW, int NW, int WNB, bool PRESCALE>
__global__ __launch_bounds__(MW * NW * 64) void k_gemm(const __hip_bfloat16* __restrict__ A,
                                                       const __hip_bfloat16* __restrict__ Wswz,
                                                       const float* __restrict__ dinvp,
                                                       unsigned short* __restrict__ Cout,
                                                       int M, int NOUT) {
    constexpr int KSTEPS = K / 32;
    const int lane = threadIdx.x & 63;
    const int wid  = threadIdx.x >> 6;
    const int wm = (wid % MW) * 64;
    const int wn = (wid / MW) * (WNB * 16);
    const long rowBase = (long)blockIdx.x * (MW * 64);
    const int cl = lane & 15, q = lane >> 4;

    const __hip_bfloat16* aptr[4];
#pragma unroll
    for (int mf = 0; mf < 4; ++mf) {
        long r = rowBase + wm + mf * 16 + cl;
        if (r > M - 1) r = M - 1;
        aptr[mf] = A + r * K + q * 8;
    }
    const __hip_bfloat16* bptr[WNB];
#pragma unroll
    for (int nf = 0; nf < WNB; ++nf) {
        int g = wn / 16 + nf;
        bptr[nf] = Wswz + (size_t)g * KSTEPS * 512 + (size_t)lane * 8;
    }

    f32x4 acc[4][WNB];
    const f32x4 z = {0.f, 0.f, 0.f, 0.f};
#pragma unroll
    for (int mf = 0; mf < 4; ++mf)
#pragma unroll
        for (int nf = 0; nf < WNB; ++nf) acc[mf][nf] = z;

#pragma unroll
    for (int ks = 0; ks < KSTEPS; ++ks) {
        bf16x8 a[4], b[WNB];
#pragma unroll
        for (int mf = 0; mf < 4; ++mf)
            a[mf] = __builtin_bit_cast(bf16x8, *(const uint4*)(aptr[mf] + ks * 32));
#pragma unroll
        for (int nf = 0; nf < WNB; ++nf)
            b[nf] = __builtin_bit_cast(bf16x8, *(const uint4*)(bptr[nf] + ks * 512));
#pragma unroll
        for (int mf = 0; mf < 4; ++mf)
#pragma unroll
            for (int nf = 0; nf < WNB; ++nf)
                acc[mf][nf] = __builtin_amdgcn_mfma_f32_16x16x32_bf16(a[mf], b[nf], acc[mf][nf], 0, 0, 0);
    }

#pragma unroll
    for (int mf = 0; mf < 4; ++mf)
#pragma unroll
        for (int i = 0; i < 4; ++i) {
            long row = rowBase + wm + mf * 16 + q * 4 + i;
            if (row >= M) continue;
            float dv = PRESCALE ? dinvp[row] : 1.0f;
#pragma unroll
            for (int nf = 0; nf < WNB; ++nf) {
                int col = wn + nf * 16 + cl;
                if (col < NOUT)
                    Cout[row * NOUT + col] = f2b(PRESCALE ? acc[mf][nf][i] * dv : acc[mf][nf][i]);
            }
        }
}

// ---------------- BN stats / params / apply ----------------
__global__ __launch_bounds__(256) void k_stats(const unsigned short* __restrict__ Zu,
                                               float* __restrict__ sums, float* __restrict__ sq) {
    const int t = threadIdx.x;
    const long r0 = (long)blockIdx.x * 256;
    float s = 0.f, s2 = 0.f;
    for (int i = 0; i < 256; ++i) {
        long r = r0 + i;
        if (r >= NNODES) break;
        float v = __uint_as_float((unsigned)Zu[r * 256 + t] << 16);
        s += v; s2 += v * v;
    }
    atomicAdd(&sums[t], s);
    atomicAdd(&sq[t], s2);
}

__global__ __launch_bounds__(256) void k_bnparams(const float* __restrict__ sums, const float* __restrict__ sq,
                                                  const float* __restrict__ gamma,
                                                  const float* __restrict__ beta,
                                                  float* __restrict__ scale, float* __restrict__ shift) {
    int t = threadIdx.x;
    float mu = sums[t] * (1.0f / NNODES);
    float var = sq[t] * (1.0f / NNODES) - mu * mu;
    if (var < 0.f) var = 0.f;
    float sc = gamma[t] * rsqrtf(var + EPS);
    scale[t] = sc;
    shift[t] = beta[t] - mu * sc;
}

__global__ __launch_bounds__(256) void k_bnrelu(const uint4* __restrict__ Z,
                                                const float* __restrict__ scale,
                                                const float* __restrict__ shift,
                                                uint4* __restrict__ H) {
    size_t t = (size_t)blockIdx.x * 256 + threadIdx.x;
    uint4 u = Z[t];
    int c0 = (int)((t * 8) & 255);
    float v[8] = {bflo(u.x), bfhi(u.x), bflo(u.y), bfhi(u.y),
                  bflo(u.z), bfhi(u.z), bflo(u.w), bfhi(u.w)};
    float r[8];
#pragma unroll
    for (int j = 0; j < 8; ++j) r[j] = fmaxf(0.f, v[j] * scale[c0 + j] + shift[c0 + j]);
    uint4 o;
    o.x = pk2(r[0], r[1]); o.y = pk2(r[2], r[3]); o.z = pk2(r[4], r[5]); o.w = pk2(r[6], r[7]);
    H[t] = o;
}

// ---------------- driver ----------------
extern "C" void kernel_launch(void* const* d_in, const int* in_sizes, int n_in,
                              void* d_out, int out_size, void* d_ws, size_t ws_size,
                              hipStream_t stream) {
    const float* x   = (const float*)d_in[0];
    const int*   ei  = (const int*)d_in[1];
    const float* W1  = (const float*)d_in[2];
    const float* g1  = (const float*)d_in[4];
    const float* be1 = (const float*)d_in[5];
    const float* W2  = (const float*)d_in[6];
    const float* g2  = (const float*)d_in[8];
    const float* be2 = (const float*)d_in[9];
    const float* W3  = (const float*)d_in[10];
    const float* b3  = (const float*)d_in[11];
    // b1 (d_in[3]) and b2 (d_in[7]) cancel exactly under BatchNorm — skipped.

    char* w = (char*)d_ws;
    size_t o = 0;
    auto alloc = [&](size_t b) { size_t r = o; o += (b + 255) & ~(size_t)255; return r; };
    int*   deg  = (int*)(w + alloc((size_t)NNODES * 4));
    int*   offs = (int*)(w + alloc((size_t)(NNODES + 1) * 4));
    float* dinv = (float*)(w + alloc((size_t)NNODES * 4));
    int*   bsum = (int*)(w + alloc(1024 * 4));
    int*   cnt  = (int*)(w + alloc((size_t)NEB * NBUCK * 4));   // 1.6 MB
    int*   btot = (int*)(w + alloc(NBUCK * 4));
    int*   bbase= (int*)(w + alloc((NBUCK + 1) * 4));
    unsigned* ebuf = (unsigned*)(w + alloc((size_t)NEDGES * 4));
    int*   csr  = (int*)(w + alloc((size_t)NEDGES * 4));
    float* stats = (float*)(w + alloc(4 * 256 * 4));
    float* bnp   = (float*)(w + alloc(4 * 256 * 4));
    __hip_bfloat16* w1s  = (__hip_bfloat16*)(w + alloc(65536));
    __hip_bfloat16* w2s  = (__hip_bfloat16*)(w + alloc(131072));
    __hip_bfloat16* w3s  = (__hip_bfloat16*)(w + alloc(24576));
    __hip_bfloat16* xb   = (__hip_bfloat16*)(w + alloc((size_t)NNODES * 128 * 2));
    __hip_bfloat16* buf0 = (__hip_bfloat16*)(w + alloc((size_t)NNODES * 128 * 2));
    __hip_bfloat16* buf1 = (__hip_bfloat16*)(w + alloc((size_t)NNODES * 256 * 2));
    __hip_bfloat16* buf2 = (__hip_bfloat16*)(w + alloc((size_t)NNODES * 256 * 2));

    float* sums1 = stats;       float* sq1 = stats + 256;
    float* sums2 = stats + 512; float* sq2 = stats + 768;
    float* scale1 = bnp;        float* shift1 = bnp + 256;
    float* scale2 = bnp + 512;  float* shift2 = bnp + 768;

    hipMemsetAsync(stats, 0, 4 * 256 * 4, stream);

    const int SB = (NNODES + 255) / 256;  // 782
    k_cnt<<<NEB, 256, 0, stream>>>(ei, cnt);
    k_bscan<<<(NBUCK * 64 + 255) / 256, 256, 0, stream>>>(cnt, btot);
    k_btscan<<<1, 1024, 0, stream>>>(btot, bbase);
    k_place<<<NEB, 256, 0, stream>>>(ei, ei + NEDGES, cnt, bbase, ebuf);
    k_ndeg<<<NBUCK, 256, 0, stream>>>(ebuf, bbase, deg);
    k_scan1<<<SB, 256, 0, stream>>>(deg, offs, bsum, dinv);
    k_scan2<<<1, 1024, 0, stream>>>(bsum, SB);
    k_scan3<<<SB, 256, 0, stream>>>(offs, bsum);
    k_sort<<<NBUCK, 256, 0, stream>>>(ebuf, offs, csr);
    k_cast<<<(NNODES * 128 / 8) / 256, 256, 0, stream>>>(x, dinv, (uint4*)xb);

    k_prepw<<<16, 256, 0, stream>>>(W1, w1s, 128, 256, 16);
    k_prepw<<<32, 256, 0, stream>>>(W2, w2s, 256, 256, 16);
    k_prepw<<<6, 256, 0, stream>>>(W3, w3s, 256, 40, 3);

    const dim3 g64((NNODES + 63) / 64, 1);

    // layer 1 (aggregate-first on prescaled bf16 x)
    k_aggf<<<NNODES / 4, 256, 0, stream>>>((const uint4*)xb, offs, csr, dinv, (uint4*)buf0);
    k_gemm<128, 1, 4, 4, false><<<g64, 256, 0, stream>>>(buf0, w1s, nullptr, (unsigned short*)buf1, NNODES, 256);
    k_stats<<<SB, 256, 0, stream>>>((const unsigned short*)buf1, sums1, sq1);
    k_bnparams<<<1, 256, 0, stream>>>(sums1, sq1, g1, be1, scale1, shift1);
    k_bnrelu<<<25000, 256, 0, stream>>>((const uint4*)buf1, scale1, shift1, (uint4*)buf2);

    // layer 2 (transform-first; gemm epilogue prescales by dinv)
    k_gemm<256, 1, 4, 4, true><<<g64, 256, 0, stream>>>(buf2, w2s, dinv, (unsigned short*)buf1, NNODES, 256);
    k_aggb<<<NNODES / 4, 256, 0, stream>>>((const uint4*)buf1, offs, csr, dinv, (uint4*)buf2);
    k_stats<<<SB, 256, 0, stream>>>((const unsigned short*)buf2, sums2, sq2);
    k_bnparams<<<1, 256, 0, stream>>>(sums2, sq2, g2, be2, scale2, shift2);
    k_bnrelu<<<25000, 256, 0, stream>>>((const uint4*)buf2, scale2, shift2, (uint4*)buf1);

    // layer 3 (transform to 40 bf16 prescaled, aggregate + log_softmax fused)
    k_gemm<256, 4, 1, 3, true><<<dim3((NNODES + 255) / 256, 1), 256, 0, stream>>>(buf1, w3s, dinv, (unsigned short*)buf0, NNODES, 40);
    k_agg3<<<NNODES / 4, 256, 0, stream>>>((const uint4*)buf0, offs, csr, dinv, b3, (float*)d_out);
}

// Round 7
// 1172.288 us; speedup vs baseline: 1.7403x; 1.0402x over previous
//
#include <hip/hip_runtime.h>
#include <hip/hip_bf16.h>

#define NNODES 200000
#define NEDGES 3200000
#define NBUCK 782            // ceil(NNODES/256)
#define NEB 512              // edge blocks for counting sort
#define EPB (NEDGES / NEB)   // 6250 edges per block
#define CASTB 12500          // NNODES*128/8/256
#define EPS 1e-5f

typedef __bf16 bf16x8 __attribute__((ext_vector_type(8)));
typedef float  f32x4  __attribute__((ext_vector_type(4)));

__device__ __forceinline__ float bflo(unsigned u) { return __uint_as_float(u << 16); }
__device__ __forceinline__ float bfhi(unsigned u) { return __uint_as_float(u & 0xffff0000u); }
__device__ __forceinline__ unsigned short f2b(float f) {
    return __builtin_bit_cast(unsigned short, __float2bfloat16(f));
}
__device__ __forceinline__ unsigned pk2(float a, float b) {
    return (unsigned)f2b(a) | ((unsigned)f2b(b) << 16);
}

// ---------------- CSR build: atomic-free two-level counting sort ----------------
__global__ __launch_bounds__(256) void k_cnt(const int* __restrict__ row, int* __restrict__ cnt) {
    __shared__ int h[NBUCK];
    for (int i = threadIdx.x; i < NBUCK; i += 256) h[i] = 0;
    __syncthreads();
    const int e0 = blockIdx.x * EPB;
    for (int i = e0 + threadIdx.x; i < e0 + EPB; i += 256)
        atomicAdd(&h[row[i] >> 8], 1);
    __syncthreads();
    for (int i = threadIdx.x; i < NBUCK; i += 256)
        cnt[(size_t)blockIdx.x * NBUCK + i] = h[i];
}

__global__ __launch_bounds__(256) void k_bscan(int* __restrict__ cnt, int* __restrict__ btot) {
    const int wv = (blockIdx.x * 256 + threadIdx.x) >> 6;   // bucket
    const int lane = threadIdx.x & 63;
    if (wv >= NBUCK) return;
    int v[8]; int s = 0;
#pragma unroll
    for (int j = 0; j < 8; ++j) {
        v[j] = cnt[(size_t)(lane * 8 + j) * NBUCK + wv];
        s += v[j];
    }
    int excl = s;
#pragma unroll
    for (int o = 1; o < 64; o <<= 1) {
        int t = __shfl_up(excl, o);
        if (lane >= o) excl += t;
    }
    excl -= s;
    if (lane == 63) btot[wv] = excl + s;
    int base = excl;
#pragma unroll
    for (int j = 0; j < 8; ++j) {
        int t = v[j];
        cnt[(size_t)(lane * 8 + j) * NBUCK + wv] = base;
        base += t;
    }
}

__global__ __launch_bounds__(1024) void k_btscan(const int* __restrict__ btot, int* __restrict__ bbase) {
    __shared__ int s[1024];
    int t = threadIdx.x;
    int v = (t < NBUCK) ? btot[t] : 0;
    s[t] = v;
    __syncthreads();
    for (int off = 1; off < 1024; off <<= 1) {
        int u = (t >= off) ? s[t - off] : 0;
        __syncthreads();
        s[t] += u;
        __syncthreads();
    }
    if (t < NBUCK) bbase[t + 1] = s[t];
    if (t == 0) bbase[0] = 0;
}

__global__ __launch_bounds__(256) void k_place(const int* __restrict__ row, const int* __restrict__ col,
                                               const int* __restrict__ cnt, const int* __restrict__ bbase,
                                               unsigned* __restrict__ ebuf) {
    __shared__ int base[NBUCK];
    for (int i = threadIdx.x; i < NBUCK; i += 256)
        base[i] = bbase[i] + cnt[(size_t)blockIdx.x * NBUCK + i];
    __syncthreads();
    const int e0 = blockIdx.x * EPB;
    for (int i = e0 + threadIdx.x; i < e0 + EPB; i += 256) {
        int r = row[i], c = col[i];
        int p = atomicAdd(&base[r >> 8], 1);
        ebuf[p] = ((unsigned)(r & 255) << 18) | (unsigned)c;   // col < 2^18
    }
}

// fused: per-bucket degree count -> offs/dinv -> rank -> final CSR
__global__ __launch_bounds__(256) void k_sort2(const unsigned* __restrict__ ebuf,
                                               const int* __restrict__ bbase,
                                               int* __restrict__ offs, float* __restrict__ dinv,
                                               int* __restrict__ csr) {
    __shared__ int cnt[256];
    __shared__ int sofs[256];
    __shared__ int sc[256];
    const int b = blockIdx.x;
    const int t = threadIdx.x;
    const int n0 = b * 256;
    cnt[t] = 0;
    __syncthreads();
    const int s = bbase[b], e = bbase[b + 1];
    for (int i = s + t; i < e; i += 256)
        atomicAdd(&cnt[ebuf[i] >> 18], 1);
    __syncthreads();
    const int c = cnt[t];
    sc[t] = c;
    __syncthreads();
    for (int off = 1; off < 256; off <<= 1) {
        int v = (t >= off) ? sc[t - off] : 0;
        __syncthreads();
        sc[t] += v;
        __syncthreads();
    }
    const int excl = sc[t] - c;
    sofs[t] = s + excl;
    const int n = n0 + t;
    if (n < NNODES) {
        offs[n] = s + excl;
        dinv[n] = rsqrtf((float)(c + 1));
    }
    if (b == NBUCK - 1 && t == 0) offs[NNODES] = NEDGES;
    cnt[t] = 0;
    __syncthreads();
    for (int i = s + t; i < e; i += 256) {
        unsigned v = ebuf[i];
        int nl = v >> 18;
        int rank = atomicAdd(&cnt[nl], 1);
        csr[sofs[nl] + rank] = (int)(v & 0x3FFFFu);
    }
}

// ---------------- fused prep: cast x (prescaled) + swizzle W1/W2/W3 ----------------
__device__ __forceinline__ void prepw_one(const float* __restrict__ W,
                                          unsigned short* __restrict__ Wswz,
                                          int K, int NOUT, int t) {
    int KSTEPS = K / 32;
    int lane = t & 63;
    int ks = (t >> 6) % KSTEPS;
    int g  = (t >> 6) / KSTEPS;
    int c = lane & 15, q = lane >> 4;
    int col = g * 16 + c;
    int k0 = ks * 32 + q * 8;
    unsigned short vals[8];
#pragma unroll
    for (int j = 0; j < 8; ++j)
        vals[j] = (col < NOUT) ? f2b(W[(size_t)(k0 + j) * NOUT + col]) : (unsigned short)0;
    *(uint4*)((char*)Wswz + (size_t)t * 16) = __builtin_bit_cast(uint4, vals);
}

__global__ __launch_bounds__(256) void k_prep(const float* __restrict__ x,
                                              const float* __restrict__ dinv,
                                              uint4* __restrict__ xb,
                                              const float* __restrict__ W1,
                                              const float* __restrict__ W2,
                                              const float* __restrict__ W3,
                                              unsigned short* __restrict__ w1s,
                                              unsigned short* __restrict__ w2s,
                                              unsigned short* __restrict__ w3s) {
    const int blk = blockIdx.x;
    if (blk < CASTB) {
        size_t t = (size_t)blk * 256 + threadIdx.x;
        int n = (int)(t >> 4);
        float d = dinv[n];
        const float4* xp = (const float4*)(x + t * 8);
        float4 a = xp[0], b = xp[1];
        uint4 o;
        o.x = pk2(a.x * d, a.y * d); o.y = pk2(a.z * d, a.w * d);
        o.z = pk2(b.x * d, b.y * d); o.w = pk2(b.z * d, b.w * d);
        xb[t] = o;
    } else {
        int t = (blk - CASTB) * 256 + threadIdx.x;
        if (t < 4096) prepw_one(W1, w1s, 128, 256, t);                     // 16*4*64
        else if (t < 4096 + 8192) prepw_one(W2, w2s, 256, 256, t - 4096);  // 16*8*64
        else if (t < 4096 + 8192 + 1536) prepw_one(W3, w3s, 256, 40, t - 12288); // 3*8*64
    }
}

// ---------------- aggregation: F=128 rows (16 x uint4), 4 edges per load ----------------
__global__ __launch_bounds__(256) void k_aggf(const uint4* __restrict__ in,
                                              const int* __restrict__ offs,
                                              const int* __restrict__ csr,
                                              const float* __restrict__ dinv,
                                              uint4* __restrict__ out) {
    const int lane = threadIdx.x & 63;
    const int grp = lane >> 4;
    const int fl = lane & 15;
    const int node = blockIdx.x * 4 + (threadIdx.x >> 6);
    const int p0 = offs[node];
    const int K = offs[node + 1] - p0 + 1;   // +1 virtual self item at k=0
    float a0=0,a1=0,a2=0,a3=0,a4=0,a5=0,a6=0,a7=0;
    auto accum = [&](uint4 u) {
        a0 += bflo(u.x); a1 += bfhi(u.x);
        a2 += bflo(u.y); a3 += bfhi(u.y);
        a4 += bflo(u.z); a5 += bfhi(u.z);
        a6 += bflo(u.w); a7 += bfhi(u.w);
    };
    int k = 0;
    for (; k + 8 <= K; k += 8) {
        int j0 = k + grp, j1 = k + 4 + grp;
        int i0 = (j0 == 0) ? node : csr[p0 + j0 - 1];
        int i1 = csr[p0 + j1 - 1];
        uint4 u0 = in[(size_t)i0 * 16 + fl];
        uint4 u1 = in[(size_t)i1 * 16 + fl];
        accum(u0); accum(u1);
    }
    for (; k + 4 <= K; k += 4) {
        int j0 = k + grp;
        int i0 = (j0 == 0) ? node : csr[p0 + j0 - 1];
        accum(in[(size_t)i0 * 16 + fl]);
    }
    int rem = K - k;
    if (grp < rem) {
        int j0 = k + grp;
        int i0 = (j0 == 0) ? node : csr[p0 + j0 - 1];
        accum(in[(size_t)i0 * 16 + fl]);
    }
#define RED(v) v += __shfl_xor(v, 32); v += __shfl_xor(v, 16);
    RED(a0) RED(a1) RED(a2) RED(a3) RED(a4) RED(a5) RED(a6) RED(a7)
#undef RED
    if (grp == 0) {
        const float d = dinv[node];
        uint4 o;
        o.x = pk2(a0 * d, a1 * d); o.y = pk2(a2 * d, a3 * d);
        o.z = pk2(a4 * d, a5 * d); o.w = pk2(a6 * d, a7 * d);
        out[(size_t)node * 16 + fl] = o;
    }
}

// ---------------- aggregation: F=256 rows (32 x uint4), 2 edges per load, unroll 4 ----------------
__global__ __launch_bounds__(256) void k_aggb(const uint4* __restrict__ in,
                                              const int* __restrict__ offs,
                                              const int* __restrict__ csr,
                                              const float* __restrict__ dinv,
                                              uint4* __restrict__ out) {
    const int lane = threadIdx.x & 63;
    const int half = lane >> 5;
    const int fl = lane & 31;
    const int node = blockIdx.x * 4 + (threadIdx.x >> 6);
    const int p0 = offs[node];
    const int K = offs[node + 1] - p0 + 1;
    float a0=0,a1=0,a2=0,a3=0,a4=0,a5=0,a6=0,a7=0;
    auto accum = [&](uint4 u) {
        a0 += bflo(u.x); a1 += bfhi(u.x);
        a2 += bflo(u.y); a3 += bfhi(u.y);
        a4 += bflo(u.z); a5 += bfhi(u.z);
        a6 += bflo(u.w); a7 += bfhi(u.w);
    };
    auto idxAt = [&](int j) -> int { return (j == 0) ? node : csr[p0 + j - 1]; };
    int k = 0;
    for (; k + 8 <= K; k += 8) {
        int i0 = idxAt(k + half);
        int i1 = csr[p0 + k + 1 + half];
        int i2 = csr[p0 + k + 3 + half];
        int i3 = csr[p0 + k + 5 + half];
        uint4 u0 = in[(size_t)i0 * 32 + fl];
        uint4 u1 = in[(size_t)i1 * 32 + fl];
        uint4 u2 = in[(size_t)i2 * 32 + fl];
        uint4 u3 = in[(size_t)i3 * 32 + fl];
        accum(u0); accum(u1); accum(u2); accum(u3);
    }
    for (; k + 2 <= K; k += 2) {
        accum(in[(size_t)idxAt(k + half) * 32 + fl]);
    }
    if (k < K && half == 0) {
        accum(in[(size_t)idxAt(k) * 32 + fl]);
    }
#define RED(v) v += __shfl_xor(v, 32);
    RED(a0) RED(a1) RED(a2) RED(a3) RED(a4) RED(a5) RED(a6) RED(a7)
#undef RED
    if (half == 0) {
        const float d = dinv[node];
        uint4 o;
        o.x = pk2(a0 * d, a1 * d); o.y = pk2(a2 * d, a3 * d);
        o.z = pk2(a4 * d, a5 * d); o.w = pk2(a6 * d, a7 * d);
        out[(size_t)node * 32 + fl] = o;
    }
}

// ---------------- final layer: 40-feat rows (5 x uint4), 12 edges per load + log_softmax ----------------
__global__ __launch_bounds__(256) void k_agg3(const uint4* __restrict__ T3b,
                                              const int* __restrict__ offs,
                                              const int* __restrict__ csr,
                                              const float* __restrict__ dinv,
                                              const float* __restrict__ b3,
                                              float* __restrict__ out) {
    const int lane = threadIdx.x & 63;
    const int grp = lane / 5;
    const int fl = lane - grp * 5;
    const bool act = grp < 12;
    const int node = blockIdx.x * 4 + (threadIdx.x >> 6);
    const int p0 = offs[node];
    const int K = offs[node + 1] - p0 + 1;
    float a0=0,a1=0,a2=0,a3=0,a4=0,a5=0,a6=0,a7=0;
    auto accum = [&](uint4 u) {
        a0 += bflo(u.x); a1 += bfhi(u.x);
        a2 += bflo(u.y); a3 += bfhi(u.y);
        a4 += bflo(u.z); a5 += bfhi(u.z);
        a6 += bflo(u.w); a7 += bfhi(u.w);
    };
    const char* Tb = (const char*)T3b;
    int k = 0;
    if (act) {
        for (; k + 12 <= K; k += 12) {
            int j = k + grp;
            int i0 = (j == 0) ? node : csr[p0 + j - 1];
            accum(*(const uint4*)(Tb + (size_t)i0 * 80 + fl * 16));
        }
        int rem = K - k;
        if (grp < rem) {
            int j = k + grp;
            int i0 = (j == 0) ? node : csr[p0 + j - 1];
            accum(*(const uint4*)(Tb + (size_t)i0 * 80 + fl * 16));
        }
    }
#define RED3(v) { float t = __shfl(v, lane + 30); v += t; t = __shfl(v, lane + 15); v += t; \
                  float u1 = __shfl(v, lane + 5); float u2 = __shfl(v, lane + 10); v += u1 + u2; }
    RED3(a0) RED3(a1) RED3(a2) RED3(a3) RED3(a4) RED3(a5) RED3(a6) RED3(a7)
#undef RED3
    const float d = dinv[node];
    float v[8];
    if (grp == 0) {
        const float4* bp = (const float4*)(b3 + fl * 8);
        float4 b01 = bp[0], b23 = bp[1];
        v[0] = a0 * d + b01.x; v[1] = a1 * d + b01.y;
        v[2] = a2 * d + b01.z; v[3] = a3 * d + b01.w;
        v[4] = a4 * d + b23.x; v[5] = a5 * d + b23.y;
        v[6] = a6 * d + b23.z; v[7] = a7 * d + b23.w;
    } else {
#pragma unroll
        for (int j = 0; j < 8; ++j) v[j] = -INFINITY;
    }
    float m = v[0];
#pragma unroll
    for (int j = 1; j < 8; ++j) m = fmaxf(m, v[j]);
    float mm = __shfl(m, 0);
#pragma unroll
    for (int l = 1; l < 5; ++l) mm = fmaxf(mm, __shfl(m, l));
    float e = 0.f;
    if (grp == 0) {
#pragma unroll
        for (int j = 0; j < 8; ++j) e += __expf(v[j] - mm);
    }
    float s = __shfl(e, 0);
#pragma unroll
    for (int l = 1; l < 5; ++l) s += __shfl(e, l);
    float ls = __logf(s);
    if (grp == 0) {
        float* op = out + (size_t)node * 40 + fl * 8;
        float4 o0 = {v[0] - mm - ls, v[1] - mm - ls, v[2] - mm - ls, v[3] - mm - ls};
        float4 o1 = {v[4] - mm - ls, v[5] - mm - ls, v[6] - mm - ls, v[7] - mm - ls};
        *(float4*)op = o0;
        *(float4*)(op + 4) = o1;
    }
}

// ---------------- MFMA GEMM with optional fused BN+ReLU on A and dinv prescale on C ----------------
template <int K, int MW, int NW, int WNB, bool PRESCALE, bool BNA>
__global__ __launch_bounds__(MW * NW * 64) void k_gemm(const __hip_bfloat16* __restrict__ A,
                                                       const __hip_bfloat16* __restrict__ Wswz,
                                                       const float* __restrict__ dinvp,
                                                       const float* __restrict__ bnsc,
                                                       const float* __restrict__ bnsh,
                                                       unsigned short* __restrict__ Cout,
                                                       int M, int NOUT) {
    constexpr int KSTEPS = K / 32;
    const int lane = threadIdx.x & 63;
    const int wid  = threadIdx.x >> 6;
    const int wm = (wid % MW) * 64;
    const int wn = (wid / MW) * (WNB * 16);
    const long rowBase = (long)blockIdx.x * (MW * 64);
    const int cl = lane & 15, q = lane >> 4;

    const __hip_bfloat16* aptr[4];
#pragma unroll
    for (int mf = 0; mf < 4; ++mf) {
        long r = rowBase + wm + mf * 16 + cl;
        if (r > M - 1) r = M - 1;
        aptr[mf] = A + r * K + q * 8;
    }
    const __hip_bfloat16* bptr[WNB];
#pragma unroll
    for (int nf = 0; nf < WNB; ++nf) {
        int g = wn / 16 + nf;
        bptr[nf] = Wswz + (size_t)g * KSTEPS * 512 + (size_t)lane * 8;
    }

    f32x4 acc[4][WNB];
    const f32x4 z = {0.f, 0.f, 0.f, 0.f};
#pragma unroll
    for (int mf = 0; mf < 4; ++mf)
#pragma unroll
        for (int nf = 0; nf < WNB; ++nf) acc[mf][nf] = z;

#pragma unroll
    for (int ks = 0; ks < KSTEPS; ++ks) {
        float4 c0, c1, h0, h1;
        if constexpr (BNA) {
            const int k0 = ks * 32 + q * 8;
            c0 = *(const float4*)(bnsc + k0); c1 = *(const float4*)(bnsc + k0 + 4);
            h0 = *(const float4*)(bnsh + k0); h1 = *(const float4*)(bnsh + k0 + 4);
        }
        bf16x8 a[4], b[WNB];
#pragma unroll
        for (int mf = 0; mf < 4; ++mf) {
            uint4 u = *(const uint4*)(aptr[mf] + ks * 32);
            if constexpr (BNA) {
                uint4 o;
                o.x = pk2(fmaxf(0.f, bflo(u.x) * c0.x + h0.x), fmaxf(0.f, bfhi(u.x) * c0.y + h0.y));
                o.y = pk2(fmaxf(0.f, bflo(u.y) * c0.z + h0.z), fmaxf(0.f, bfhi(u.y) * c0.w + h0.w));
                o.z = pk2(fmaxf(0.f, bflo(u.z) * c1.x + h1.x), fmaxf(0.f, bfhi(u.z) * c1.y + h1.y));
                o.w = pk2(fmaxf(0.f, bflo(u.w) * c1.z + h1.z), fmaxf(0.f, bfhi(u.w) * c1.w + h1.w));
                u = o;
            }
            a[mf] = __builtin_bit_cast(bf16x8, u);
        }
#pragma unroll
        for (int nf = 0; nf < WNB; ++nf)
            b[nf] = __builtin_bit_cast(bf16x8, *(const uint4*)(bptr[nf] + ks * 512));
#pragma unroll
        for (int mf = 0; mf < 4; ++mf)
#pragma unroll
            for (int nf = 0; nf < WNB; ++nf)
                acc[mf][nf] = __builtin_amdgcn_mfma_f32_16x16x32_bf16(a[mf], b[nf], acc[mf][nf], 0, 0, 0);
    }

#pragma unroll
    for (int mf = 0; mf < 4; ++mf)
#pragma unroll
        for (int i = 0; i < 4; ++i) {
            long row = rowBase + wm + mf * 16 + q * 4 + i;
            if (row >= M) continue;
            float dv = PRESCALE ? dinvp[row] : 1.0f;
#pragma unroll
            for (int nf = 0; nf < WNB; ++nf) {
                int col = wn + nf * 16 + cl;
                if (col < NOUT)
                    Cout[row * NOUT + col] = f2b(PRESCALE ? acc[mf][nf][i] * dv : acc[mf][nf][i]);
            }
        }
}

// ---------------- BN stats; last block computes scale/shift ----------------
__global__ __launch_bounds__(256) void k_stats(const unsigned short* __restrict__ Zu,
                                               float* __restrict__ sums, float* __restrict__ sq,
                                               const float* __restrict__ gamma,
                                               const float* __restrict__ beta,
                                               float* __restrict__ scale, float* __restrict__ shift,
                                               int* __restrict__ done, int nblocks) {
    const int t = threadIdx.x;
    const long r0 = (long)blockIdx.x * 256;
    float s = 0.f, s2 = 0.f;
    for (int i = 0; i < 256; ++i) {
        long r = r0 + i;
        if (r >= NNODES) break;
        float v = __uint_as_float((unsigned)Zu[r * 256 + t] << 16);
        s += v; s2 += v * v;
    }
    atomicAdd(&sums[t], s);
    atomicAdd(&sq[t], s2);
    __syncthreads();                       // drains this block's atomics (vmcnt(0) before barrier)
    __shared__ int lastf;
    if (t == 0) lastf = (atomicAdd(done, 1) == nblocks - 1) ? 1 : 0;
    __syncthreads();
    if (lastf) {
        float su = atomicAdd(&sums[t], 0.0f);   // L2-coherent read
        float qu = atomicAdd(&sq[t], 0.0f);
        float mu = su * (1.0f / NNODES);
        float var = qu * (1.0f / NNODES) - mu * mu;
        if (var < 0.f) var = 0.f;
        float sc = gamma[t] * rsqrtf(var + EPS);
        scale[t] = sc;
        shift[t] = beta[t] - mu * sc;
    }
}

// ---------------- driver ----------------
extern "C" void kernel_launch(void* const* d_in, const int* in_sizes, int n_in,
                              void* d_out, int out_size, void* d_ws, size_t ws_size,
                              hipStream_t stream) {
    const float* x   = (const float*)d_in[0];
    const int*   ei  = (const int*)d_in[1];
    const float* W1  = (const float*)d_in[2];
    const float* g1  = (const float*)d_in[4];
    const float* be1 = (const float*)d_in[5];
    const float* W2  = (const float*)d_in[6];
    const float* g2  = (const float*)d_in[8];
    const float* be2 = (const float*)d_in[9];
    const float* W3  = (const float*)d_in[10];
    const float* b3  = (const float*)d_in[11];
    // b1 (d_in[3]) and b2 (d_in[7]) cancel exactly under BatchNorm — skipped.

    char* w = (char*)d_ws;
    size_t o = 0;
    auto alloc = [&](size_t b) { size_t r = o; o += (b + 255) & ~(size_t)255; return r; };
    int*   offs = (int*)(w + alloc((size_t)(NNODES + 1) * 4));
    float* dinv = (float*)(w + alloc((size_t)NNODES * 4));
    int*   cnt  = (int*)(w + alloc((size_t)NEB * NBUCK * 4));   // 1.6 MB
    int*   btot = (int*)(w + alloc(NBUCK * 4));
    int*   bbase= (int*)(w + alloc((NBUCK + 1) * 4));
    unsigned* ebuf = (unsigned*)(w + alloc((size_t)NEDGES * 4));
    int*   csr  = (int*)(w + alloc((size_t)NEDGES * 4));
    float* stats = (float*)(w + alloc(4 * 256 * 4 + 32));       // sums1,sq1,sums2,sq2,done1,done2
    float* bnp   = (float*)(w + alloc(4 * 256 * 4));            // scale1,shift1,scale2,shift2
    unsigned short* w1s = (unsigned short*)(w + alloc(65536));
    unsigned short* w2s = (unsigned short*)(w + alloc(131072));
    unsigned short* w3s = (unsigned short*)(w + alloc(24576));
    __hip_bfloat16* xb   = (__hip_bfloat16*)(w + alloc((size_t)NNODES * 128 * 2));
    __hip_bfloat16* buf0 = (__hip_bfloat16*)(w + alloc((size_t)NNODES * 128 * 2)); // y0 -> T3'
    __hip_bfloat16* buf1 = (__hip_bfloat16*)(w + alloc((size_t)NNODES * 256 * 2)); // Z1 -> Z2
    __hip_bfloat16* buf2 = (__hip_bfloat16*)(w + alloc((size_t)NNODES * 256 * 2)); // y2'

    float* sums1 = stats;       float* sq1 = stats + 256;
    float* sums2 = stats + 512; float* sq2 = stats + 768;
    int*   done1 = (int*)(stats + 1024);
    int*   done2 = done1 + 1;
    float* scale1 = bnp;        float* shift1 = bnp + 256;
    float* scale2 = bnp + 512;  float* shift2 = bnp + 768;

    hipMemsetAsync(stats, 0, 4 * 256 * 4 + 32, stream);

    const int SB = (NNODES + 255) / 256;  // 782
    k_cnt<<<NEB, 256, 0, stream>>>(ei, cnt);
    k_bscan<<<(NBUCK * 64 + 255) / 256, 256, 0, stream>>>(cnt, btot);
    k_btscan<<<1, 1024, 0, stream>>>(btot, bbase);
    k_place<<<NEB, 256, 0, stream>>>(ei, ei + NEDGES, cnt, bbase, ebuf);
    k_sort2<<<NBUCK, 256, 0, stream>>>(ebuf, bbase, offs, dinv, csr);
    k_prep<<<CASTB + 54, 256, 0, stream>>>(x, dinv, (uint4*)xb, W1, W2, W3, w1s, w2s, w3s);

    const dim3 g64((NNODES + 63) / 64, 1);

    // layer 1
    k_aggf<<<NNODES / 4, 256, 0, stream>>>((const uint4*)xb, offs, csr, dinv, (uint4*)buf0);
    k_gemm<128, 1, 4, 4, false, false><<<g64, 256, 0, stream>>>(buf0, (const __hip_bfloat16*)w1s, nullptr, nullptr, nullptr, (unsigned short*)buf1, NNODES, 256);
    k_stats<<<SB, 256, 0, stream>>>((const unsigned short*)buf1, sums1, sq1, g1, be1, scale1, shift1, done1, SB);

    // layer 2: gemm2 applies BN1+ReLU on A inline, prescales C by dinv
    k_gemm<256, 1, 4, 4, true, true><<<g64, 256, 0, stream>>>(buf1, (const __hip_bfloat16*)w2s, dinv, scale1, shift1, (unsigned short*)buf2, NNODES, 256);
    k_aggb<<<NNODES / 4, 256, 0, stream>>>((const uint4*)buf2, offs, csr, dinv, (uint4*)buf1);
    k_stats<<<SB, 256, 0, stream>>>((const unsigned short*)buf1, sums2, sq2, g2, be2, scale2, shift2, done2, SB);

    // layer 3: gemm3 applies BN2+ReLU on A inline, prescales C by dinv; then fused agg+softmax
    k_gemm<256, 4, 1, 3, true, true><<<dim3((NNODES + 255) / 256, 1), 256, 0, stream>>>(buf1, (const __hip_bfloat16*)w3s, dinv, scale2, shift2, (unsigned short*)buf0, NNODES, 40);
    k_agg3<<<NNODES / 4, 256, 0, stream>>>((const uint4*)buf0, offs, csr, dinv, b3, (float*)d_out);
}